// Round 1
// baseline (18893.292 us; speedup 1.0000x reference)
//
#include <hip/hip_runtime.h>
#include <hip/hip_bf16.h>
#include <math.h>

// HybridLoss: 0.2 * chamfer(gt->pred) + 0.8 * sinkhorn_divergence(pred, gt)
// Sinkhorn in scaling (u-v) domain: u = a / (K v), v = b / (K^T u),
// K_ij = exp(-sqrt(d2_ij + 1e-12)/eps).  50 iterations, eps = 0.05.
// value = mean(f) + mean(g), f = eps*(ln u + ln N), g = eps*(ln v + ln N).

#define PN 8192              // points per cloud
#define EPS 0.05f
// -log2(e)/eps
#define KNEG (-28.853900817779268f)
#define LN_N 9.010913347279289f   // ln(8192)

#if defined(__has_builtin) && __has_builtin(__builtin_amdgcn_exp2f)
#define EXP2F __builtin_amdgcn_exp2f
#else
#define EXP2F exp2f
#endif
#if defined(__has_builtin) && __has_builtin(__builtin_amdgcn_sqrtf)
#define SQRTF __builtin_amdgcn_sqrtf
#else
#define SQRTF sqrtf
#endif

// ws layout (bytes):
//   Wg      : 3 * 8192 * 16 = 393216   (col-side packed x,y,z,v)
//   Wf      : 3 * 8192 * 16 = 393216   (row-side packed x,y,z,u)
//   partial : 3 * 2 * 8192 * 4 = 196608
//   counters: 768 * 4
//   chamsum : 4
#define WS_WG   0
#define WS_WF   393216
#define WS_PART 786432
#define WS_CNT  983040
#define WS_CHAM 986112

__global__ __launch_bounds__(256) void init_kernel(
    const float4* __restrict__ pred, const float4* __restrict__ gt,
    float4* __restrict__ Wg, int* __restrict__ counters, float* __restrict__ chamsum)
{
    int idx = blockIdx.x * 256 + threadIdx.x;
    if (idx < 3 * PN) {
        int p = idx >> 13;
        int j = idx & (PN - 1);
        // column points: p=0 (xy): gt, p=1 (xx): pred, p=2 (yy): gt
        const float4* c = (p == 1) ? pred : gt;
        float4 v = c[j];
        Wg[idx] = make_float4(v.x, v.y, v.z, 1.0f / 8192.0f);  // v = b
    }
    if (idx < 768) counters[idx] = 0;
    if (idx == 0) *chamsum = 0.0f;
}

// One half-update (dir=0: f/u update over rows; dir=1: g/v update over cols)
// for all 3 problems.  Grid: 768 blocks = 3 problems x 128 rowblocks x 2 chunks.
// Each block: 64 rows, 4 waves each cover 1024 columns of its 4096-col chunk.
__global__ __launch_bounds__(256) void pass_kernel(
    const float4* __restrict__ pred, const float4* __restrict__ gt,
    const float4* __restrict__ W_in, float4* __restrict__ W_out,
    float* __restrict__ partial, int* __restrict__ counters, const int dir)
{
    const int bid = blockIdx.x;
    const int p = bid >> 8;           // problem 0..2
    const int rem = bid & 255;
    const int chunk = rem & 1;        // column chunk 0..1
    const int rb = rem >> 1;          // rowblock 0..127
    const int tid = threadIdx.x;
    const int lane = tid & 63;
    const int wave = __builtin_amdgcn_readfirstlane(tid >> 6);

    // row-side points: dir=0 rows are {pred,pred,gt}; dir=1 rows are {gt,pred,gt}
    const float4* rowpts = (p == 1) ? pred : (p == 2 ? gt : (dir ? gt : pred));

    const int row = (rb << 6) + lane;
    const float4 rp = rowpts[row];
    const float rx = rp.x, ry = rp.y, rz = rp.z;

    const float4* Wp = W_in + (p << 13) + (chunk << 12) + (wave << 10);
    float acc = 0.0f;
#pragma unroll 4
    for (int jj = 0; jj < 1024; ++jj) {
        float4 w = Wp[jj];                       // wave-uniform -> s_load
        float dx = rx - w.x, dy = ry - w.y, dz = rz - w.z;
        float d2 = fmaf(dx, dx, fmaf(dy, dy, fmaf(dz, dz, 1e-12f)));
        float c = SQRTF(d2);
        float e = EXP2F(c * KNEG);               // K_ij
        acc = fmaf(e, w.w, acc);                 // += K * v_j
    }

    __shared__ float red[4][64];
    __shared__ int lastFlag;
    red[wave][lane] = acc;
    __syncthreads();
    if (tid < 64) {
        float s = red[0][tid] + red[1][tid] + red[2][tid] + red[3][tid];
        partial[(((p << 1) + chunk) << 13) + (rb << 6) + tid] = s;
    }
    __threadfence();
    __syncthreads();
    const int cidx = dir * 384 + (p << 7) + rb;
    if (tid == 0) {
        int old = __hip_atomic_fetch_add(&counters[cidx], 1,
                                         __ATOMIC_ACQ_REL, __HIP_MEMORY_SCOPE_AGENT);
        lastFlag = (old == 1);
    }
    __syncthreads();
    if (lastFlag) {
        __threadfence();   // acquire: see the other chunk's partial
        if (tid < 64) {
            int r = (rb << 6) + tid;
            float s = partial[((p << 1) << 13) + r] +
                      partial[(((p << 1) + 1) << 13) + r];
            float fac = (1.0f / 8192.0f) / s;   // u = a / (K v)
            float4 q = rowpts[r];
            W_out[(p << 13) + r] = make_float4(q.x, q.y, q.z, fac);
        }
        if (tid == 0) counters[cidx] = 0;       // ready for next iteration
    }
}

// chamfer = mean_i min_j ||gt_i - pred_j||^2 ; 128 blocks x 64 rows
__global__ __launch_bounds__(256) void chamfer_kernel(
    const float4* __restrict__ pred, const float4* __restrict__ gt,
    float* __restrict__ chamsum)
{
    const int tid = threadIdx.x;
    const int lane = tid & 63;
    const int wave = __builtin_amdgcn_readfirstlane(tid >> 6);
    const int row = blockIdx.x * 64 + lane;
    const float4 rp = gt[row];
    const float rx = rp.x, ry = rp.y, rz = rp.z;
    const float4* Wp = pred + (wave << 11);
    float m = 3.4e38f;
#pragma unroll 4
    for (int jj = 0; jj < 2048; ++jj) {
        float4 w = Wp[jj];
        float dx = rx - w.x, dy = ry - w.y, dz = rz - w.z;
        float d2 = fmaf(dx, dx, fmaf(dy, dy, dz * dz));
        m = fminf(m, d2);
    }
    __shared__ float red[4][64];
    red[wave][lane] = m;
    __syncthreads();
    if (tid < 64) {
        float mm = fminf(fminf(red[0][tid], red[1][tid]),
                         fminf(red[2][tid], red[3][tid]));
        for (int off = 32; off; off >>= 1) mm += __shfl_xor(mm, off, 64);
        if (tid == 0) atomicAdd(chamsum, mm);
    }
}

__global__ __launch_bounds__(256) void final_kernel(
    const float4* __restrict__ Wf, const float4* __restrict__ Wg,
    const float* __restrict__ chamsum, float* __restrict__ out)
{
    const int tid = threadIdx.x;
    __shared__ float red[3][256];
    for (int p = 0; p < 3; ++p) {
        float local = 0.0f;
        for (int i = tid; i < PN; i += 256)
            local += logf(Wf[(p << 13) + i].w) + logf(Wg[(p << 13) + i].w);
        red[p][tid] = local;
    }
    __syncthreads();
    if (tid == 0) {
        float v[3];
        for (int p = 0; p < 3; ++p) {
            float t = 0.0f;
            for (int k = 0; k < 256; ++k) t += red[p][k];
            // mean(f)+mean(g) = eps*( (S_lnU + S_lnV)/N + 2*ln N )
            v[p] = EPS * (t / 8192.0f + 2.0f * LN_N);
        }
        float emd = v[0] - 0.5f * v[1] - 0.5f * v[2];
        float cham = (*chamsum) / 8192.0f;
        out[0] = 0.2f * cham + 0.8f * emd;
    }
}

extern "C" void kernel_launch(void* const* d_in, const int* in_sizes, int n_in,
                              void* d_out, int out_size, void* d_ws, size_t ws_size,
                              hipStream_t stream)
{
    const float4* pred = (const float4*)d_in[0];   // (8192,4) f32
    const float4* gt   = (const float4*)d_in[1];   // (8192,4) f32
    char* ws = (char*)d_ws;
    float4* Wg      = (float4*)(ws + WS_WG);
    float4* Wf      = (float4*)(ws + WS_WF);
    float*  partial = (float*)(ws + WS_PART);
    int*    counters= (int*)(ws + WS_CNT);
    float*  chamsum = (float*)(ws + WS_CHAM);
    float*  out     = (float*)d_out;

    init_kernel<<<96, 256, 0, stream>>>(pred, gt, Wg, counters, chamsum);
    chamfer_kernel<<<128, 256, 0, stream>>>(pred, gt, chamsum);
    for (int it = 0; it < 50; ++it) {
        pass_kernel<<<768, 256, 0, stream>>>(pred, gt, Wg, Wf, partial, counters, 0);
        pass_kernel<<<768, 256, 0, stream>>>(pred, gt, Wf, Wg, partial, counters, 1);
    }
    final_kernel<<<1, 256, 0, stream>>>(Wf, Wg, chamsum, out);
}

// Round 3
// 5960.477 us; speedup vs baseline: 3.1698x; 3.1698x over previous
//
#include <hip/hip_runtime.h>
#include <hip/hip_bf16.h>
#include <math.h>

// HybridLoss = 0.2 * chamfer(gt->pred) + 0.8 * sinkhorn_divergence(pred, gt)
// Sinkhorn in scaling (u-v) domain; coords pre-scaled by S = log2(e)/eps so
// K_ij = exp2(-sqrt(S^2*(d2+1e-12))) needs no multiply in the inner loop.
// Quad arrays hold (S*x, S*y, S*z, ||S*p||^2) -- static across iterations.
// Only factor arrays (Vf = a*u, Vg = b*v) are rewritten each half-pass.

#define PN 8192
#define EPS 0.05f
#define SCALE 28.853900817779268f        // log2(e)/eps
#define LN_N 9.010913347279289f          // ln(8192)
#define EPS_SCALED 8.3255e-10f           // SCALE^2 * 1e-12
#define INV_S2 (1.0f / (SCALE * SCALE))
#define LN2 0.6931471805599453f
#define TILE 2048

#define EXP2F __builtin_amdgcn_exp2f
#define SQRTF __builtin_amdgcn_sqrtf
#if defined(__has_builtin) && __has_builtin(__builtin_amdgcn_logf)
#define LOG2F __builtin_amdgcn_logf
#else
#define LOG2F log2f
#endif

// ws layout (bytes)
#define WS_QP   0          // 8192 float4 = 131072
#define WS_QG   131072     // 131072
#define WS_VF   262144     // 3*8192*4 = 98304
#define WS_VG   360448     // 98304
#define WS_CHAM 458752     // 4

__global__ __launch_bounds__(256) void init_kernel(
    const float4* __restrict__ pred, const float4* __restrict__ gt,
    float4* __restrict__ QP, float4* __restrict__ QG,
    float* __restrict__ Vg, float* __restrict__ chamsum)
{
    int idx = blockIdx.x * 256 + threadIdx.x;
    if (idx < PN) {
        float4 p = pred[idx];
        float px = p.x * SCALE, py = p.y * SCALE, pz = p.z * SCALE;
        QP[idx] = make_float4(px, py, pz, fmaf(px, px, fmaf(py, py, pz * pz)));
        float4 g = gt[idx];
        float gx = g.x * SCALE, gy = g.y * SCALE, gz = g.z * SCALE;
        QG[idx] = make_float4(gx, gy, gz, fmaf(gx, gx, fmaf(gy, gy, gz * gz)));
    }
    if (idx < 3 * PN) Vg[idx] = 1.0f / 8192.0f;
    if (idx == 0) *chamsum = 0.0f;
}

// One half-update for all 3 problems. Grid: 768 = 3 problems x 256 rowblocks.
// Block: 32 complete rows (r = tid&31), 8 column chunks (c = tid>>5).
// Columns staged in LDS tiles of 2048; inner reads are LDS broadcasts.
__global__ __launch_bounds__(256) void pass_kernel(
    const float4* __restrict__ QP, const float4* __restrict__ QG,
    float* __restrict__ Vf, float* __restrict__ Vg, const int dir)
{
    const int tid = threadIdx.x;
    const int p = blockIdx.x >> 8;       // problem 0..2
    const int rb = blockIdx.x & 255;     // rowblock
    const int r = tid & 31;
    const int c = tid >> 5;

    // dir0 rows: A[p] = {QP,QP,QG}; cols B[p] = {QG,QP,QG}. dir1 swaps.
    const float4* Aq = (p == 2) ? QG : QP;
    const float4* Bq = (p == 1) ? QP : QG;
    const float4* rowQ = dir ? Bq : Aq;
    const float4* colQ = dir ? Aq : Bq;
    const float* vin  = (dir ? Vf : Vg) + p * PN;
    float*       vout = (dir ? Vg : Vf) + p * PN;

    const int row = rb * 32 + r;
    const float4 rq = rowQ[row];
    const float r2x = -2.0f * rq.x, r2y = -2.0f * rq.y, r2z = -2.0f * rq.z;
    const float base = rq.w;             // ||r'||^2

    __shared__ float4 sQ[TILE];
    __shared__ float4 sV4[TILE / 4];
    float* sV = (float*)sV4;

    float acc = 0.0f;
    for (int tb = 0; tb < PN; tb += TILE) {
        __syncthreads();
#pragma unroll
        for (int k = 0; k < TILE / 256; ++k) {
            int idx = tid + k * 256;
            sQ[idx] = colQ[tb + idx];     // coalesced float4
            sV[idx] = vin[tb + idx];
        }
        __syncthreads();
        const float4* q  = sQ + c * (TILE / 8);
        const float4* v4 = sV4 + c * (TILE / 32);
#pragma unroll 2
        for (int j4 = 0; j4 < TILE / 32; ++j4) {
            float4 vv = v4[j4];
#pragma unroll
            for (int k = 0; k < 4; ++k) {
                float4 w = q[j4 * 4 + k];
                float t = base + w.w;
                t = fmaf(r2x, w.x, t);
                t = fmaf(r2y, w.y, t);
                t = fmaf(r2z, w.z, t);
                t = fmaxf(t, EPS_SCALED);       // clamp + the +1e-12
                float d = SQRTF(t);
                float e = EXP2F(-d);            // K_ij (neg modifier free)
                float vk = (k == 0) ? vv.x : (k == 1) ? vv.y : (k == 2) ? vv.z : vv.w;
                acc = fmaf(e, vk, acc);
            }
        }
    }

    __shared__ float red[8][33];
    red[c][r] = acc;
    __syncthreads();
    if (tid < 32) {
        float s = red[0][tid] + red[1][tid] + red[2][tid] + red[3][tid]
                + red[4][tid] + red[5][tid] + red[6][tid] + red[7][tid];
        vout[rb * 32 + tid] = (1.0f / 8192.0f) / s;   // u = a / (K v)
    }
}

// chamfer = mean_i min_j ||gt_i - pred_j||^2 over scaled quads (monotone).
__global__ __launch_bounds__(256) void chamfer_kernel(
    const float4* __restrict__ QP, const float4* __restrict__ QG,
    float* __restrict__ chamsum)
{
    const int tid = threadIdx.x;
    const int rb = blockIdx.x;
    const int r = tid & 31;
    const int c = tid >> 5;
    const int row = rb * 32 + r;
    const float4 rq = QG[row];
    const float r2x = -2.0f * rq.x, r2y = -2.0f * rq.y, r2z = -2.0f * rq.z;

    __shared__ float4 sQ[TILE];
    float m = 3.4e38f;
    for (int tb = 0; tb < PN; tb += TILE) {
        __syncthreads();
#pragma unroll
        for (int k = 0; k < TILE / 256; ++k) {
            int idx = tid + k * 256;
            sQ[idx] = QP[tb + idx];
        }
        __syncthreads();
        const float4* q = sQ + c * (TILE / 8);
#pragma unroll 4
        for (int jj = 0; jj < TILE / 8; ++jj) {
            float4 w = q[jj];
            float t = fmaf(r2x, w.x, w.w);
            t = fmaf(r2y, w.y, t);
            t = fmaf(r2z, w.z, t);
            m = fminf(m, t);                 // min of (cc - 2 r.c)
        }
    }
    __shared__ float red[8][33];
    red[c][r] = m;
    __syncthreads();
    if (tid < 32) {
        float mm = fminf(fminf(fminf(red[0][tid], red[1][tid]),
                               fminf(red[2][tid], red[3][tid])),
                         fminf(fminf(red[4][tid], red[5][tid]),
                               fminf(red[6][tid], red[7][tid])));
        float d2 = fmaxf(mm + rq.w, 0.0f) * INV_S2;   // + ||r||^2, unscale
        // sum the 32 row results within wave 0
        for (int off = 16; off; off >>= 1) d2 += __shfl_xor(d2, off, 64);
        if (tid == 0) atomicAdd(chamsum, d2);
    }
}

__global__ __launch_bounds__(256) void final_kernel(
    const float* __restrict__ Vf, const float* __restrict__ Vg,
    const float* __restrict__ chamsum, float* __restrict__ out)
{
    const int tid = threadIdx.x;
    // weighted sum of logs; the 2*ln(N) constants cancel (1 - 0.5 - 0.5 = 0)
    float local = 0.0f;
    for (int i = tid; i < PN; i += 256) {
        float w0 = LOG2F(Vf[i]) + LOG2F(Vg[i]);
        float w1 = LOG2F(Vf[PN + i]) + LOG2F(Vg[PN + i]);
        float w2 = LOG2F(Vf[2 * PN + i]) + LOG2F(Vg[2 * PN + i]);
        local += w0 - 0.5f * (w1 + w2);
    }
    for (int off = 32; off; off >>= 1) local += __shfl_xor(local, off, 64);
    __shared__ float red[4];
    if ((tid & 63) == 0) red[tid >> 6] = local;
    __syncthreads();
    if (tid == 0) {
        float wsum = red[0] + red[1] + red[2] + red[3];
        float emd = EPS * LN2 * wsum / 8192.0f;   // log2 -> ln, mean f + mean g
        float cham = (*chamsum) / 8192.0f;
        out[0] = 0.2f * cham + 0.8f * emd;
    }
}

extern "C" void kernel_launch(void* const* d_in, const int* in_sizes, int n_in,
                              void* d_out, int out_size, void* d_ws, size_t ws_size,
                              hipStream_t stream)
{
    const float4* pred = (const float4*)d_in[0];   // (8192,4) f32
    const float4* gt   = (const float4*)d_in[1];
    char* ws = (char*)d_ws;
    float4* QP      = (float4*)(ws + WS_QP);
    float4* QG      = (float4*)(ws + WS_QG);
    float*  Vf      = (float*)(ws + WS_VF);
    float*  Vg      = (float*)(ws + WS_VG);
    float*  chamsum = (float*)(ws + WS_CHAM);
    float*  out     = (float*)d_out;

    init_kernel<<<96, 256, 0, stream>>>(pred, gt, QP, QG, Vg, chamsum);
    chamfer_kernel<<<256, 256, 0, stream>>>(QP, QG, chamsum);
    for (int it = 0; it < 50; ++it) {
        pass_kernel<<<768, 256, 0, stream>>>(QP, QG, Vf, Vg, 0);
        pass_kernel<<<768, 256, 0, stream>>>(QP, QG, Vf, Vg, 1);
    }
    final_kernel<<<1, 256, 0, stream>>>(Vf, Vg, chamsum, out);
}

// Round 4
// 5418.039 us; speedup vs baseline: 3.4871x; 1.1001x over previous
//
#include <hip/hip_runtime.h>
#include <hip/hip_bf16.h>
#include <math.h>

// HybridLoss = 0.2 * chamfer(gt->pred) + 0.8 * sinkhorn_divergence(pred, gt)
// Sinkhorn in scaling (u-v) domain; coords pre-scaled by S = log2(e)/eps so
// K_ij = exp2(-sqrt(S^2*(d2+1e-12))) needs no multiply in the inner loop.
// Quad arrays hold (S*x, S*y, S*z, ||S*p||^2) -- static across iterations.

#define PN 8192
#define EPS 0.05f
#define SCALE 28.853900817779268f        // log2(e)/eps
#define INV_S2 (1.0f / (SCALE * SCALE))
#define LN2 0.6931471805599453f
#define TILE 2048

#define EXP2F __builtin_amdgcn_exp2f
#define SQRTF __builtin_amdgcn_sqrtf
#if defined(__has_builtin) && __has_builtin(__builtin_amdgcn_logf)
#define LOG2F __builtin_amdgcn_logf
#else
#define LOG2F log2f
#endif

// ws layout (bytes)
#define WS_QP   0          // 8192 float4 = 131072
#define WS_QG   131072     // 131072
#define WS_VF   262144     // 3*8192*4 = 98304
#define WS_VG   360448     // 98304
#define WS_CHAM 458752     // 4

__global__ __launch_bounds__(256) void init_kernel(
    const float4* __restrict__ pred, const float4* __restrict__ gt,
    float4* __restrict__ QP, float4* __restrict__ QG,
    float* __restrict__ Vg, float* __restrict__ chamsum)
{
    int idx = blockIdx.x * 256 + threadIdx.x;
    if (idx < PN) {
        float4 p = pred[idx];
        float px = p.x * SCALE, py = p.y * SCALE, pz = p.z * SCALE;
        QP[idx] = make_float4(px, py, pz, fmaf(px, px, fmaf(py, py, pz * pz)));
        float4 g = gt[idx];
        float gx = g.x * SCALE, gy = g.y * SCALE, gz = g.z * SCALE;
        QG[idx] = make_float4(gx, gy, gz, fmaf(gx, gx, fmaf(gy, gy, gz * gz)));
    }
    if (idx < 3 * PN) Vg[idx] = 1.0f / 8192.0f;
    if (idx == 0) *chamsum = 0.0f;
}

// One half-update for all 3 problems. Grid: 768 = 3 problems x 256 rowblocks.
// Block: 512 threads = 32 rows (r=tid&31) x 16 column chunks (c=tid>>5).
// Per wave: 32 rows x 2 chunks -> 2 distinct LDS addresses (free broadcast).
__global__ __launch_bounds__(512) void pass_kernel(
    const float4* __restrict__ QP, const float4* __restrict__ QG,
    float* __restrict__ Vf, float* __restrict__ Vg, const int dir)
{
    const int tid = threadIdx.x;
    const int p = blockIdx.x >> 8;       // problem 0..2
    const int rb = blockIdx.x & 255;     // rowblock
    const int r = tid & 31;
    const int c = tid >> 5;              // 0..15, chunk of 128 cols per tile

    // dir0 rows: A[p] = {QP,QP,QG}; cols B[p] = {QG,QP,QG}. dir1 swaps.
    const float4* Aq = (p == 2) ? QG : QP;
    const float4* Bq = (p == 1) ? QP : QG;
    const float4* rowQ = dir ? Bq : Aq;
    const float4* colQ = dir ? Aq : Bq;
    float* vin  = (dir ? Vf : Vg) + p * PN;
    float* vout = (dir ? Vg : Vf) + p * PN;

    const int row = rb * 32 + r;
    const float4 rq = rowQ[row];
    const float r2x = -2.0f * rq.x, r2y = -2.0f * rq.y, r2z = -2.0f * rq.z;
    const float base = rq.w;             // ||r'||^2

    __shared__ float4 sQ[TILE];
    __shared__ float4 sV4[TILE / 4];
    float* sV = (float*)sV4;

    float acc = 0.0f;
    for (int tb = 0; tb < PN; tb += TILE) {
        __syncthreads();
#pragma unroll
        for (int k = 0; k < TILE / 512; ++k) {
            int idx = tid + k * 512;
            sQ[idx] = colQ[tb + idx];     // coalesced float4
            sV[idx] = vin[tb + idx];
        }
        __syncthreads();
        const float4* q  = sQ + c * (TILE / 16);
        const float4* v4 = sV4 + c * (TILE / 64);
#pragma unroll 4
        for (int j4 = 0; j4 < TILE / 64; ++j4) {
            float4 vv = v4[j4];
#pragma unroll
            for (int k = 0; k < 4; ++k) {
                float4 w = q[j4 * 4 + k];
                float t = base + w.w;
                t = fmaf(r2x, w.x, t);
                t = fmaf(r2y, w.y, t);
                t = fmaf(r2z, w.z, t);
                float d = SQRTF(fabsf(t));      // abs = free input modifier
                float e = EXP2F(-d);            // K_ij (neg modifier free)
                float vk = (k == 0) ? vv.x : (k == 1) ? vv.y : (k == 2) ? vv.z : vv.w;
                acc = fmaf(e, vk, acc);
            }
        }
    }

    __shared__ float red[16][33];
    red[c][r] = acc;
    __syncthreads();
    if (tid < 32) {
        float s = 0.0f;
#pragma unroll
        for (int c2 = 0; c2 < 16; ++c2) s += red[c2][tid];
        vout[rb * 32 + tid] = (1.0f / 8192.0f) / s;   // u = a / (K v)
    }
}

// chamfer = mean_i min_j ||gt_i - pred_j||^2 over scaled quads (monotone).
// 512 blocks x 512 threads: 16 rows (r=tid&15) x 32 chunks (c=tid>>4).
__global__ __launch_bounds__(512) void chamfer_kernel(
    const float4* __restrict__ QP, const float4* __restrict__ QG,
    float* __restrict__ chamsum)
{
    const int tid = threadIdx.x;
    const int rb = blockIdx.x;
    const int r = tid & 15;
    const int c = tid >> 4;
    const int row = rb * 16 + r;
    const float4 rq = QG[row];
    const float r2x = -2.0f * rq.x, r2y = -2.0f * rq.y, r2z = -2.0f * rq.z;

    __shared__ float4 sQ[TILE];
    float m = 3.4e38f;
    for (int tb = 0; tb < PN; tb += TILE) {
        __syncthreads();
#pragma unroll
        for (int k = 0; k < TILE / 512; ++k) {
            int idx = tid + k * 512;
            sQ[idx] = QP[tb + idx];
        }
        __syncthreads();
        const float4* q = sQ + c * (TILE / 32);
#pragma unroll 4
        for (int jj = 0; jj < TILE / 32; ++jj) {
            float4 w = q[jj];
            float t = fmaf(r2x, w.x, w.w);
            t = fmaf(r2y, w.y, t);
            t = fmaf(r2z, w.z, t);
            m = fminf(m, t);                 // min of (cc - 2 r.c)
        }
    }
    __shared__ float red[32][17];
    red[c][r] = m;
    __syncthreads();
    if (tid < 16) {
        float mm = 3.4e38f;
#pragma unroll
        for (int c2 = 0; c2 < 32; ++c2) mm = fminf(mm, red[c2][tid]);
        float d2 = fmaxf(mm + rq.w, 0.0f) * INV_S2;   // + ||r||^2, unscale
        // sum the 16 row results (lanes 0..15 of wave 0)
        for (int off = 8; off; off >>= 1) d2 += __shfl_xor(d2, off, 64);
        if (tid == 0) atomicAdd(chamsum, d2);
    }
}

__global__ __launch_bounds__(256) void final_kernel(
    const float* __restrict__ Vf, const float* __restrict__ Vg,
    const float* __restrict__ chamsum, float* __restrict__ out)
{
    const int tid = threadIdx.x;
    // weighted sum of logs; the 2*ln(N) constants cancel (1 - 0.5 - 0.5 = 0)
    float local = 0.0f;
    for (int i = tid; i < PN; i += 256) {
        float w0 = LOG2F(Vf[i]) + LOG2F(Vg[i]);
        float w1 = LOG2F(Vf[PN + i]) + LOG2F(Vg[PN + i]);
        float w2 = LOG2F(Vf[2 * PN + i]) + LOG2F(Vg[2 * PN + i]);
        local += w0 - 0.5f * (w1 + w2);
    }
    for (int off = 32; off; off >>= 1) local += __shfl_xor(local, off, 64);
    __shared__ float red[4];
    if ((tid & 63) == 0) red[tid >> 6] = local;
    __syncthreads();
    if (tid == 0) {
        float wsum = red[0] + red[1] + red[2] + red[3];
        float emd = EPS * LN2 * wsum / 8192.0f;   // log2 -> ln, mean f + mean g
        float cham = (*chamsum) / 8192.0f;
        out[0] = 0.2f * cham + 0.8f * emd;
    }
}

extern "C" void kernel_launch(void* const* d_in, const int* in_sizes, int n_in,
                              void* d_out, int out_size, void* d_ws, size_t ws_size,
                              hipStream_t stream)
{
    const float4* pred = (const float4*)d_in[0];   // (8192,4) f32
    const float4* gt   = (const float4*)d_in[1];
    char* ws = (char*)d_ws;
    float4* QP      = (float4*)(ws + WS_QP);
    float4* QG      = (float4*)(ws + WS_QG);
    float*  Vf      = (float*)(ws + WS_VF);
    float*  Vg      = (float*)(ws + WS_VG);
    float*  chamsum = (float*)(ws + WS_CHAM);
    float*  out     = (float*)d_out;

    init_kernel<<<96, 256, 0, stream>>>(pred, gt, QP, QG, Vg, chamsum);
    chamfer_kernel<<<512, 512, 0, stream>>>(QP, QG, chamsum);
    for (int it = 0; it < 50; ++it) {
        pass_kernel<<<768, 512, 0, stream>>>(QP, QG, Vf, Vg, 0);
        pass_kernel<<<768, 512, 0, stream>>>(QP, QG, Vf, Vg, 1);
    }
    final_kernel<<<1, 256, 0, stream>>>(Vf, Vg, chamsum, out);
}

// Round 5
// 5285.546 us; speedup vs baseline: 3.5745x; 1.0251x over previous
//
#include <hip/hip_runtime.h>
#include <hip/hip_bf16.h>
#include <math.h>

// HybridLoss = 0.2 * chamfer(gt->pred) + 0.8 * sinkhorn_divergence(pred, gt)
// Sinkhorn in scaling (u-v) domain; coords pre-scaled by S = log2(e)/eps so
// K_ij = exp2(-sqrt(S^2*(d2+1e-12))) needs no multiply in the inner loop.
// R5: register-block 4 rows/thread so one LDS quad read serves 4 elements
// (R4 was DS-pipe-bound at ~10cy/b128, 154k cy/CU/pass).

#define PN 8192
#define EPS 0.05f
#define SCALE 28.853900817779268f        // log2(e)/eps
#define INV_S2 (1.0f / (SCALE * SCALE))
#define LN2 0.6931471805599453f
#define TILE 2048

#define EXP2F __builtin_amdgcn_exp2f
#define SQRTF __builtin_amdgcn_sqrtf
#if defined(__has_builtin) && __has_builtin(__builtin_amdgcn_logf)
#define LOG2F __builtin_amdgcn_logf
#else
#define LOG2F log2f
#endif

// ws layout (bytes)
#define WS_QP   0          // 8192 float4 = 131072
#define WS_QG   131072     // 131072
#define WS_VF   262144     // 3*8192*4 = 98304
#define WS_VG   360448     // 98304
#define WS_CHAM 458752     // 4

__global__ __launch_bounds__(256) void init_kernel(
    const float4* __restrict__ pred, const float4* __restrict__ gt,
    float4* __restrict__ QP, float4* __restrict__ QG,
    float* __restrict__ Vg, float* __restrict__ chamsum)
{
    int idx = blockIdx.x * 256 + threadIdx.x;
    if (idx < PN) {
        float4 p = pred[idx];
        float px = p.x * SCALE, py = p.y * SCALE, pz = p.z * SCALE;
        QP[idx] = make_float4(px, py, pz, fmaf(px, px, fmaf(py, py, pz * pz)));
        float4 g = gt[idx];
        float gx = g.x * SCALE, gy = g.y * SCALE, gz = g.z * SCALE;
        QG[idx] = make_float4(gx, gy, gz, fmaf(gx, gx, fmaf(gy, gy, gz * gz)));
    }
    if (idx < 3 * PN) Vg[idx] = 1.0f / 8192.0f;
    if (idx == 0) *chamsum = 0.0f;
}

// One half-update for all 3 problems. Grid: 768 = 3 problems x 256 rowblocks.
// Block: 512 threads = 8 row-groups (x4 rows) x 64 column chunks.
// Per wave: 8 row-groups x 8 chunks; chunk-staggered LDS reads hit all 8
// bank-quads with 8-way broadcast (free) -> conflict-free.
__global__ __launch_bounds__(512) void pass_kernel(
    const float4* __restrict__ QP, const float4* __restrict__ QG,
    float* __restrict__ Vf, float* __restrict__ Vg, const int dir)
{
    const int tid = threadIdx.x;
    const int p = blockIdx.x >> 8;       // problem 0..2
    const int rb = blockIdx.x & 255;     // rowblock (32 rows)
    const int r = tid & 7;               // row-group
    const int c = tid >> 3;              // column chunk 0..63

    // dir0 rows: A[p] = {QP,QP,QG}; cols B[p] = {QG,QP,QG}. dir1 swaps.
    const float4* Aq = (p == 2) ? QG : QP;
    const float4* Bq = (p == 1) ? QP : QG;
    const float4* rowQ = dir ? Bq : Aq;
    const float4* colQ = dir ? Aq : Bq;
    float* vin  = (dir ? Vf : Vg) + p * PN;
    float* vout = (dir ? Vg : Vf) + p * PN;

    const int row0 = rb * 32 + r * 4;
    float r2x[4], r2y[4], r2z[4], base[4], acc[4];
#pragma unroll
    for (int k = 0; k < 4; ++k) {
        float4 rq = rowQ[row0 + k];
        r2x[k] = -2.0f * rq.x; r2y[k] = -2.0f * rq.y; r2z[k] = -2.0f * rq.z;
        base[k] = rq.w;
        acc[k] = 0.0f;
    }

    __shared__ float4 sQ[TILE];
    __shared__ float4 sV4[TILE / 4];
    float* sV = (float*)sV4;
    const float4* vin4 = (const float4*)vin;

    const int cbase = c * (TILE / 64);   // 32 columns per chunk per tile

    for (int tb = 0; tb < PN; tb += TILE) {
        __syncthreads();
#pragma unroll
        for (int k = 0; k < TILE / 512; ++k) {
            int idx = tid + k * 512;
            sQ[idx] = colQ[tb + idx];     // coalesced float4
        }
        sV4[tid] = vin4[tb / 4 + tid];
        __syncthreads();
#pragma unroll 4
        for (int j = 0; j < TILE / 64; ++j) {
            int col = cbase + ((j + c) & (TILE / 64 - 1));  // stagger by chunk
            float4 w = sQ[col];
            float v = sV[col];
#pragma unroll
            for (int k = 0; k < 4; ++k) {
                float t = base[k] + w.w;
                t = fmaf(r2x[k], w.x, t);
                t = fmaf(r2y[k], w.y, t);
                t = fmaf(r2z[k], w.z, t);
                float d = SQRTF(fabsf(t));
                float e = EXP2F(-d);            // K_ij
                acc[k] = fmaf(e, v, acc[k]);
            }
        }
    }

    // reduce over the wave's 8 chunks (lanes l, l^8, l^16, l^32 share row-group)
#pragma unroll
    for (int k = 0; k < 4; ++k) {
        acc[k] += __shfl_xor(acc[k], 8, 64);
        acc[k] += __shfl_xor(acc[k], 16, 64);
        acc[k] += __shfl_xor(acc[k], 32, 64);
    }
    __shared__ float red[8][33];         // [wave][row-in-block]
    const int lane = tid & 63;
    const int wave = tid >> 6;
    if (lane < 8) {
#pragma unroll
        for (int k = 0; k < 4; ++k) red[wave][lane * 4 + k] = acc[k];
    }
    __syncthreads();
    if (tid < 32) {
        float s = 0.0f;
#pragma unroll
        for (int w2 = 0; w2 < 8; ++w2) s += red[w2][tid];
        vout[rb * 32 + tid] = (1.0f / 8192.0f) / s;   // u = a / (K v)
    }
}

// chamfer = mean_i min_j ||gt_i - pred_j||^2 over scaled quads (monotone).
// 256 blocks x 512 threads: 8 row-groups (x4 rows) x 64 chunks.
__global__ __launch_bounds__(512) void chamfer_kernel(
    const float4* __restrict__ QP, const float4* __restrict__ QG,
    float* __restrict__ chamsum)
{
    const int tid = threadIdx.x;
    const int rb = blockIdx.x;
    const int r = tid & 7;
    const int c = tid >> 3;
    const int row0 = rb * 32 + r * 4;

    float r2x[4], r2y[4], r2z[4], m[4];
#pragma unroll
    for (int k = 0; k < 4; ++k) {
        float4 rq = QG[row0 + k];
        r2x[k] = -2.0f * rq.x; r2y[k] = -2.0f * rq.y; r2z[k] = -2.0f * rq.z;
        m[k] = 3.4e38f;
    }

    __shared__ float4 sQ[TILE];
    const int cbase = c * (TILE / 64);
    for (int tb = 0; tb < PN; tb += TILE) {
        __syncthreads();
#pragma unroll
        for (int k = 0; k < TILE / 512; ++k) {
            int idx = tid + k * 512;
            sQ[idx] = QP[tb + idx];
        }
        __syncthreads();
#pragma unroll 4
        for (int j = 0; j < TILE / 64; ++j) {
            int col = cbase + ((j + c) & (TILE / 64 - 1));
            float4 w = sQ[col];
#pragma unroll
            for (int k = 0; k < 4; ++k) {
                float t = fmaf(r2x[k], w.x, w.w);
                t = fmaf(r2y[k], w.y, t);
                t = fmaf(r2z[k], w.z, t);
                m[k] = fminf(m[k], t);           // min of (cc - 2 r.c)
            }
        }
    }
#pragma unroll
    for (int k = 0; k < 4; ++k) {
        m[k] = fminf(m[k], __shfl_xor(m[k], 8, 64));
        m[k] = fminf(m[k], __shfl_xor(m[k], 16, 64));
        m[k] = fminf(m[k], __shfl_xor(m[k], 32, 64));
    }
    __shared__ float red[8][33];
    const int lane = tid & 63;
    const int wave = tid >> 6;
    if (lane < 8) {
#pragma unroll
        for (int k = 0; k < 4; ++k) red[wave][lane * 4 + k] = m[k];
    }
    __syncthreads();
    if (tid < 32) {
        float mm = 3.4e38f;
#pragma unroll
        for (int w2 = 0; w2 < 8; ++w2) mm = fminf(mm, red[w2][tid]);
        float rw = QG[rb * 32 + tid].w;
        float d2 = fmaxf(mm + rw, 0.0f) * INV_S2;   // + ||r||^2, unscale
        // sum 32 row results (lanes 0..31 stay in-range for offsets <=16)
        for (int off = 16; off; off >>= 1) d2 += __shfl_xor(d2, off, 64);
        if (tid == 0) atomicAdd(chamsum, d2);
    }
}

__global__ __launch_bounds__(256) void final_kernel(
    const float* __restrict__ Vf, const float* __restrict__ Vg,
    const float* __restrict__ chamsum, float* __restrict__ out)
{
    const int tid = threadIdx.x;
    // weighted sum of logs; the 2*ln(N) constants cancel (1 - 0.5 - 0.5 = 0)
    float local = 0.0f;
    for (int i = tid; i < PN; i += 256) {
        float w0 = LOG2F(Vf[i]) + LOG2F(Vg[i]);
        float w1 = LOG2F(Vf[PN + i]) + LOG2F(Vg[PN + i]);
        float w2 = LOG2F(Vf[2 * PN + i]) + LOG2F(Vg[2 * PN + i]);
        local += w0 - 0.5f * (w1 + w2);
    }
    for (int off = 32; off; off >>= 1) local += __shfl_xor(local, off, 64);
    __shared__ float red[4];
    if ((tid & 63) == 0) red[tid >> 6] = local;
    __syncthreads();
    if (tid == 0) {
        float wsum = red[0] + red[1] + red[2] + red[3];
        float emd = EPS * LN2 * wsum / 8192.0f;   // log2 -> ln, mean f + mean g
        float cham = (*chamsum) / 8192.0f;
        out[0] = 0.2f * cham + 0.8f * emd;
    }
}

extern "C" void kernel_launch(void* const* d_in, const int* in_sizes, int n_in,
                              void* d_out, int out_size, void* d_ws, size_t ws_size,
                              hipStream_t stream)
{
    const float4* pred = (const float4*)d_in[0];   // (8192,4) f32
    const float4* gt   = (const float4*)d_in[1];
    char* ws = (char*)d_ws;
    float4* QP      = (float4*)(ws + WS_QP);
    float4* QG      = (float4*)(ws + WS_QG);
    float*  Vf      = (float*)(ws + WS_VF);
    float*  Vg      = (float*)(ws + WS_VG);
    float*  chamsum = (float*)(ws + WS_CHAM);
    float*  out     = (float*)d_out;

    init_kernel<<<96, 256, 0, stream>>>(pred, gt, QP, QG, Vg, chamsum);
    chamfer_kernel<<<256, 512, 0, stream>>>(QP, QG, chamsum);
    for (int it = 0; it < 50; ++it) {
        pass_kernel<<<768, 512, 0, stream>>>(QP, QG, Vf, Vg, 0);
        pass_kernel<<<768, 512, 0, stream>>>(QP, QG, Vf, Vg, 1);
    }
    final_kernel<<<1, 256, 0, stream>>>(Vf, Vg, chamsum, out);
}

// Round 6
// 4796.901 us; speedup vs baseline: 3.9386x; 1.1019x over previous
//
#include <hip/hip_runtime.h>
#include <hip/hip_bf16.h>
#include <math.h>

// HybridLoss = 0.2 * chamfer(gt->pred) + 0.8 * sinkhorn_divergence(pred, gt)
// Sinkhorn in scaling (u-v) domain; coords pre-scaled by S = log2(e)/eps so
// K_ij = exp2(-sqrt(S^2*(d2+1e-12))): distances are measured in "bits".
// R6: trans-pipe is the floor (~13cy each, 2/element) -> reduce ELEMENTS:
// counting-sort both clouds by 16^3 grid cell, then cull 64-column tiles
// whose bbox distance guarantees contribution < 2^-30 of the row sum.
// Per-rowblock min log2(s) from the previous pass bounds both the row sums
// and the v-magnitudes (log2 v = -13 - log2 s), making the test exact.

#define PN 8192
#define EPS 0.05f
#define SCALE 28.853900817779268f        // log2(e)/eps
#define INV_S2 (1.0f / (SCALE * SCALE))
#define LN2 0.6931471805599453f
#define TILE 2048
#define MARGIN 30.0f

#define EXP2F __builtin_amdgcn_exp2f
#define SQRTF __builtin_amdgcn_sqrtf
#if defined(__has_builtin) && __has_builtin(__builtin_amdgcn_logf)
#define LOG2F __builtin_amdgcn_logf
#else
#define LOG2F log2f
#endif

// ws layout (bytes)
#define WS_QP    0          // 8192 float4 = 131072 (sorted, scaled pred)
#define WS_QG    131072     // 131072 (sorted, scaled gt)
#define WS_VF    262144     // 3*8192*4 = 98304
#define WS_VG    360448     // 98304
#define WS_BB32  458752     // 2 clouds * 256 rb * 2 float4 = 16384
#define WS_BB64  475136     // 2 clouds * 128 t  * 2 float4 = 8192
#define WS_SARR  483328     // 2 dir * 3 p * 256 rb * 4 = 6144
#define WS_CHAM  489472     // 4

// Counting sort one cloud by 16^3 spatial cell; emits scaled quads
// (S*x, S*y, S*z, ||S*p||^2) in cell order. One block per cloud.
__global__ __launch_bounds__(1024) void sort_kernel(
    const float4* __restrict__ pred, const float4* __restrict__ gt,
    float4* __restrict__ QP, float4* __restrict__ QG)
{
    const int cloud = blockIdx.x;            // 0: pred->QP, 1: gt->QG
    const float4* src = cloud ? gt : pred;
    float4* dst = cloud ? QG : QP;
    const int tid = threadIdx.x;

    __shared__ int hist[4096];
    __shared__ int part[1024];
#pragma unroll
    for (int k = 0; k < 4; ++k) hist[tid * 4 + k] = 0;
    __syncthreads();

    int keys[8];
#pragma unroll
    for (int k = 0; k < 8; ++k) {
        float4 v = src[tid * 8 + k];
        int cx = min(15, max(0, (int)floorf((v.x + 5.0f) * 1.6f)));
        int cy = min(15, max(0, (int)floorf((v.y + 5.0f) * 1.6f)));
        int cz = min(15, max(0, (int)floorf((v.z + 5.0f) * 1.6f)));
        keys[k] = (cz << 8) | (cy << 4) | cx;
        atomicAdd(&hist[keys[k]], 1);
    }
    __syncthreads();
    int h[4], s4 = 0;
#pragma unroll
    for (int k = 0; k < 4; ++k) { h[k] = hist[tid * 4 + k]; s4 += h[k]; }
    part[tid] = s4;
    __syncthreads();
    for (int off = 1; off < 1024; off <<= 1) {      // inclusive scan
        int v = (tid >= off) ? part[tid - off] : 0;
        __syncthreads();
        part[tid] += v;
        __syncthreads();
    }
    int base = part[tid] - s4;                       // exclusive
#pragma unroll
    for (int k = 0; k < 4; ++k) { hist[tid * 4 + k] = base; base += h[k]; }
    __syncthreads();
#pragma unroll
    for (int k = 0; k < 8; ++k) {
        float4 v = src[tid * 8 + k];
        int pos = atomicAdd(&hist[keys[k]], 1);
        float x = v.x * SCALE, y = v.y * SCALE, z = v.z * SCALE;
        dst[pos] = make_float4(x, y, z, fmaf(x, x, fmaf(y, y, z * z)));
    }
}

// bboxes of 32-point groups (rowblocks). 512 blocks: cloud = b>>8, rb = b&255.
__global__ __launch_bounds__(64) void bbox32_kernel(
    const float4* __restrict__ QP, const float4* __restrict__ QG,
    float4* __restrict__ bb32)
{
    const int b = blockIdx.x;
    const float4* q = (b >> 8) ? QG : QP;
    const int lane = threadIdx.x;
    float4 v = q[(b & 255) * 32 + (lane & 31)];
    float lx = v.x, ly = v.y, lz = v.z, hx = v.x, hy = v.y, hz = v.z;
#pragma unroll
    for (int off = 1; off <= 16; off <<= 1) {
        lx = fminf(lx, __shfl_xor(lx, off, 64));
        ly = fminf(ly, __shfl_xor(ly, off, 64));
        lz = fminf(lz, __shfl_xor(lz, off, 64));
        hx = fmaxf(hx, __shfl_xor(hx, off, 64));
        hy = fmaxf(hy, __shfl_xor(hy, off, 64));
        hz = fmaxf(hz, __shfl_xor(hz, off, 64));
    }
    if (lane == 0) {
        bb32[b * 2]     = make_float4(lx, ly, lz, 0.0f);
        bb32[b * 2 + 1] = make_float4(hx, hy, hz, 0.0f);
    }
}

// bboxes of 64-point tiles = union of two 32-groups. 1 block x 256 threads.
__global__ __launch_bounds__(256) void bbox64_kernel(
    const float4* __restrict__ bb32, float4* __restrict__ bb64)
{
    const int t = threadIdx.x;               // cloud = t>>7, tile = t&127
    const int cloud = t >> 7, tile = t & 127;
    const int s = (cloud * 256 + tile * 2) * 2;
    float4 lo0 = bb32[s], hi0 = bb32[s + 1], lo1 = bb32[s + 2], hi1 = bb32[s + 3];
    bb64[t * 2] = make_float4(fminf(lo0.x, lo1.x), fminf(lo0.y, lo1.y),
                              fminf(lo0.z, lo1.z), 0.0f);
    bb64[t * 2 + 1] = make_float4(fmaxf(hi0.x, hi1.x), fmaxf(hi0.y, hi1.y),
                                  fmaxf(hi0.z, hi1.z), 0.0f);
}

__global__ __launch_bounds__(256) void init_kernel(
    float* __restrict__ Vg, float* __restrict__ SArr, float* __restrict__ chamsum)
{
    int idx = blockIdx.x * 256 + threadIdx.x;
    if (idx < 3 * PN) Vg[idx] = 1.0f / 8192.0f;
    if (idx < 1536) SArr[idx] = -1e30f;       // keep-all until real stats exist
    if (idx == 0) *chamsum = 0.0f;
}

// One half-update for all 3 problems. Grid: 768 = 3 problems x 256 rowblocks.
// Block: 512 threads = 8 row-groups (x4 rows) x 64 column slots.
// Stage 2048 cols; lane-parallel bbox cull of its 32 64-col subtiles ->
// ballot mask -> iterate survivors only.
__global__ __launch_bounds__(512) void pass_kernel(
    const float4* __restrict__ QP, const float4* __restrict__ QG,
    float* __restrict__ Vf, float* __restrict__ Vg,
    const float4* __restrict__ bb32, const float4* __restrict__ bb64,
    float* __restrict__ SArr, const int dir)
{
    const int tid = threadIdx.x;
    const int p = blockIdx.x >> 8;       // problem 0..2
    const int rb = blockIdx.x & 255;     // rowblock (32 rows)
    const int rg = tid & 7;              // row-group (4 rows)
    const int c = tid >> 3;              // column slot 0..63

    // cloud ids: 0 = pred(QP), 1 = gt(QG)
    const int r0 = (p == 2) ? 1 : 0;     // dir0 row cloud
    const int c0 = (p == 1) ? 0 : 1;     // dir0 col cloud
    const int rowCloud = dir ? c0 : r0;
    const int colCloud = dir ? r0 : c0;
    const float4* rowQ = rowCloud ? QG : QP;
    const float4* colQ = colCloud ? QG : QP;
    float* vin  = (dir ? Vf : Vg) + p * PN;
    float* vout = (dir ? Vg : Vf) + p * PN;
    const float* SArrRow = SArr + (dir * 3 + p) * 256;          // stale (prev iter)
    const float* SArrCol = SArr + ((dir ^ 1) * 3 + p) * 256;    // fresh (prev pass)

    const int row0 = rb * 32 + rg * 4;
    float r2x[4], r2y[4], r2z[4], base[4], acc[4];
#pragma unroll
    for (int k = 0; k < 4; ++k) {
        float4 rq = rowQ[row0 + k];
        r2x[k] = -2.0f * rq.x; r2y[k] = -2.0f * rq.y; r2z[k] = -2.0f * rq.z;
        base[k] = rq.w;
        acc[k] = 0.0f;
    }
    const float4 rblo = bb32[(rowCloud * 256 + rb) * 2];
    const float4 rbhi = bb32[(rowCloud * 256 + rb) * 2 + 1];
    const float minlogS = SArrRow[rb];

    __shared__ float4 sQ[TILE];
    __shared__ float4 sV4[TILE / 4];
    float* sV = (float*)sV4;
    const float4* vin4 = (const float4*)vin;

    for (int tb = 0; tb < PN; tb += TILE) {
        __syncthreads();
#pragma unroll
        for (int k = 0; k < TILE / 512; ++k) {
            int idx = tid + k * 512;
            sQ[idx] = colQ[tb + idx];     // coalesced float4
        }
        sV4[tid] = vin4[tb / 4 + tid];
        __syncthreads();

        // lane-parallel cull of this stage's 32 subtiles (64 cols each)
        unsigned long long mask;
        {
            const int L = tid & 63;
            bool keep = false;
            if (L < 32) {
                int t64 = (tb >> 6) + L;
                float4 clo = bb64[(colCloud * 128 + t64) * 2];
                float4 chi = bb64[(colCloud * 128 + t64) * 2 + 1];
                float sc = fminf(SArrCol[2 * t64], SArrCol[2 * t64 + 1]);
                float maxh = -13.0f - sc;            // max log2 v in tile
                float thr = fmaxf(maxh - minlogS + MARGIN, 0.0f);
                float dx = fmaxf(0.0f, fmaxf(rblo.x - chi.x, clo.x - rbhi.x));
                float dy = fmaxf(0.0f, fmaxf(rblo.y - chi.y, clo.y - rbhi.y));
                float dz = fmaxf(0.0f, fmaxf(rblo.z - chi.z, clo.z - rbhi.z));
                float dmin2 = fmaf(dx, dx, fmaf(dy, dy, dz * dz));
                keep = dmin2 <= thr * thr;
            }
            mask = __ballot(keep);
        }
        while (mask) {
            int st = __builtin_ctzll(mask);
            mask &= mask - 1;
            int col = st * 64 + c;
            float4 w = sQ[col];
            float v = sV[col];
#pragma unroll
            for (int k = 0; k < 4; ++k) {
                float t = base[k] + w.w;
                t = fmaf(r2x[k], w.x, t);
                t = fmaf(r2y[k], w.y, t);
                t = fmaf(r2z[k], w.z, t);
                float d = SQRTF(fabsf(t));
                float e = EXP2F(-d);            // K_ij
                acc[k] = fmaf(e, v, acc[k]);
            }
        }
    }

    // reduce over the wave's 8 column slots (lanes l^8, l^16, l^32 share rg)
#pragma unroll
    for (int k = 0; k < 4; ++k) {
        acc[k] += __shfl_xor(acc[k], 8, 64);
        acc[k] += __shfl_xor(acc[k], 16, 64);
        acc[k] += __shfl_xor(acc[k], 32, 64);
    }
    __shared__ float red[8][33];         // [wave][row-in-block]
    const int lane = tid & 63;
    const int wave = tid >> 6;
    if (lane < 8) {
#pragma unroll
        for (int k = 0; k < 4; ++k) red[wave][lane * 4 + k] = acc[k];
    }
    __syncthreads();
    if (tid < 64) {
        float s = 1.0f;
        if (tid < 32) {
            s = 0.0f;
#pragma unroll
            for (int w2 = 0; w2 < 8; ++w2) s += red[w2][tid];
            vout[rb * 32 + tid] = (1.0f / 8192.0f) / s;   // u = a / (K v)
        }
        float ls = (tid < 32) ? LOG2F(s) : 1e30f;
#pragma unroll
        for (int off = 1; off <= 32; off <<= 1)
            ls = fminf(ls, __shfl_xor(ls, off, 64));
        if (tid == 0) SArr[(dir * 3 + p) * 256 + rb] = ls;  // min log2 s
    }
}

// chamfer = mean_i min_j ||gt_i - pred_j||^2 over scaled quads (monotone).
// 256 blocks x 512 threads: 8 row-groups (x4 rows) x 64 chunks.
__global__ __launch_bounds__(512) void chamfer_kernel(
    const float4* __restrict__ QP, const float4* __restrict__ QG,
    float* __restrict__ chamsum)
{
    const int tid = threadIdx.x;
    const int rb = blockIdx.x;
    const int r = tid & 7;
    const int c = tid >> 3;
    const int row0 = rb * 32 + r * 4;

    float r2x[4], r2y[4], r2z[4], m[4];
#pragma unroll
    for (int k = 0; k < 4; ++k) {
        float4 rq = QG[row0 + k];
        r2x[k] = -2.0f * rq.x; r2y[k] = -2.0f * rq.y; r2z[k] = -2.0f * rq.z;
        m[k] = 3.4e38f;
    }

    __shared__ float4 sQ[TILE];
    const int cbase = c * (TILE / 64);
    for (int tb = 0; tb < PN; tb += TILE) {
        __syncthreads();
#pragma unroll
        for (int k = 0; k < TILE / 512; ++k) {
            int idx = tid + k * 512;
            sQ[idx] = QP[tb + idx];
        }
        __syncthreads();
#pragma unroll 4
        for (int j = 0; j < TILE / 64; ++j) {
            int col = cbase + ((j + c) & (TILE / 64 - 1));
            float4 w = sQ[col];
#pragma unroll
            for (int k = 0; k < 4; ++k) {
                float t = fmaf(r2x[k], w.x, w.w);
                t = fmaf(r2y[k], w.y, t);
                t = fmaf(r2z[k], w.z, t);
                m[k] = fminf(m[k], t);           // min of (cc - 2 r.c)
            }
        }
    }
#pragma unroll
    for (int k = 0; k < 4; ++k) {
        m[k] = fminf(m[k], __shfl_xor(m[k], 8, 64));
        m[k] = fminf(m[k], __shfl_xor(m[k], 16, 64));
        m[k] = fminf(m[k], __shfl_xor(m[k], 32, 64));
    }
    __shared__ float red[8][33];
    const int lane = tid & 63;
    const int wave = tid >> 6;
    if (lane < 8) {
#pragma unroll
        for (int k = 0; k < 4; ++k) red[wave][lane * 4 + k] = m[k];
    }
    __syncthreads();
    if (tid < 32) {
        float mm = 3.4e38f;
#pragma unroll
        for (int w2 = 0; w2 < 8; ++w2) mm = fminf(mm, red[w2][tid]);
        float rw = QG[rb * 32 + tid].w;
        float d2 = fmaxf(mm + rw, 0.0f) * INV_S2;   // + ||r||^2, unscale
        for (int off = 16; off; off >>= 1) d2 += __shfl_xor(d2, off, 64);
        if (tid == 0) atomicAdd(chamsum, d2);
    }
}

__global__ __launch_bounds__(256) void final_kernel(
    const float* __restrict__ Vf, const float* __restrict__ Vg,
    const float* __restrict__ chamsum, float* __restrict__ out)
{
    const int tid = threadIdx.x;
    float local = 0.0f;
    for (int i = tid; i < PN; i += 256) {
        float w0 = LOG2F(Vf[i]) + LOG2F(Vg[i]);
        float w1 = LOG2F(Vf[PN + i]) + LOG2F(Vg[PN + i]);
        float w2 = LOG2F(Vf[2 * PN + i]) + LOG2F(Vg[2 * PN + i]);
        local += w0 - 0.5f * (w1 + w2);
    }
    for (int off = 32; off; off >>= 1) local += __shfl_xor(local, off, 64);
    __shared__ float red[4];
    if ((tid & 63) == 0) red[tid >> 6] = local;
    __syncthreads();
    if (tid == 0) {
        float wsum = red[0] + red[1] + red[2] + red[3];
        float emd = EPS * LN2 * wsum / 8192.0f;   // log2 -> ln; ln N terms cancel
        float cham = (*chamsum) / 8192.0f;
        out[0] = 0.2f * cham + 0.8f * emd;
    }
}

extern "C" void kernel_launch(void* const* d_in, const int* in_sizes, int n_in,
                              void* d_out, int out_size, void* d_ws, size_t ws_size,
                              hipStream_t stream)
{
    const float4* pred = (const float4*)d_in[0];   // (8192,4) f32
    const float4* gt   = (const float4*)d_in[1];
    char* ws = (char*)d_ws;
    float4* QP      = (float4*)(ws + WS_QP);
    float4* QG      = (float4*)(ws + WS_QG);
    float*  Vf      = (float*)(ws + WS_VF);
    float*  Vg      = (float*)(ws + WS_VG);
    float4* bb32    = (float4*)(ws + WS_BB32);
    float4* bb64    = (float4*)(ws + WS_BB64);
    float*  SArr    = (float*)(ws + WS_SARR);
    float*  chamsum = (float*)(ws + WS_CHAM);
    float*  out     = (float*)d_out;

    sort_kernel<<<2, 1024, 0, stream>>>(pred, gt, QP, QG);
    init_kernel<<<96, 256, 0, stream>>>(Vg, SArr, chamsum);
    bbox32_kernel<<<512, 64, 0, stream>>>(QP, QG, bb32);
    bbox64_kernel<<<1, 256, 0, stream>>>(bb32, bb64);
    chamfer_kernel<<<256, 512, 0, stream>>>(QP, QG, chamsum);
    for (int it = 0; it < 50; ++it) {
        pass_kernel<<<768, 512, 0, stream>>>(QP, QG, Vf, Vg, bb32, bb64, SArr, 0);
        pass_kernel<<<768, 512, 0, stream>>>(QP, QG, Vf, Vg, bb32, bb64, SArr, 1);
    }
    final_kernel<<<1, 256, 0, stream>>>(Vf, Vg, chamsum, out);
}

// Round 7
// 4176.828 us; speedup vs baseline: 4.5234x; 1.1485x over previous
//
#include <hip/hip_runtime.h>
#include <hip/hip_bf16.h>
#include <math.h>

// HybridLoss = 0.2 * chamfer(gt->pred) + 0.8 * sinkhorn_divergence(pred, gt)
// Sinkhorn in scaling (u-v) domain; coords pre-scaled by S = log2(e)/eps so
// K_ij = exp2(-sqrt(S^2*(d2+1e-12))): distances measured in "bits".
// R7: per-WAVE culling. Wave w of block b owns rowgroup b+256w (4 rows,
// scattered across the sorted order -> static load balance), 64 col slots.
// Tile cull test per wave: 4-row bbox + per-4-row min log2 s (tight), vs
// 64-col bbox + per-tile max log2 v. MARGIN=28 bits.

#define PN 8192
#define EPS 0.05f
#define SCALE 28.853900817779268f        // log2(e)/eps
#define INV_S2 (1.0f / (SCALE * SCALE))
#define LN2 0.6931471805599453f
#define TILE 2048
#define MARGIN 28.0f

#define EXP2F __builtin_amdgcn_exp2f
#define SQRTF __builtin_amdgcn_sqrtf
#if defined(__has_builtin) && __has_builtin(__builtin_amdgcn_logf)
#define LOG2F __builtin_amdgcn_logf
#else
#define LOG2F log2f
#endif

// ws layout (bytes)
#define WS_QP    0          // 8192 float4 = 131072 (sorted, scaled pred)
#define WS_QG    131072     // 131072 (sorted, scaled gt)
#define WS_VF    262144     // 3*8192*4 = 98304
#define WS_VG    360448     // 98304
#define WS_BB32  458752     // 2 clouds * 256 * 2 float4 = 16384
#define WS_BB64  475136     // 2 clouds * 128 * 2 float4 = 8192
#define WS_SARR  483328     // 2 dir * 3 p * 2048 rg * 4 = 49152
#define WS_CHAM  532480     // 4

// Counting sort one cloud by 16^3 spatial cell; emits scaled quads
// (S*x, S*y, S*z, ||S*p||^2) in cell order. One block per cloud.
__global__ __launch_bounds__(1024) void sort_kernel(
    const float4* __restrict__ pred, const float4* __restrict__ gt,
    float4* __restrict__ QP, float4* __restrict__ QG)
{
    const int cloud = blockIdx.x;            // 0: pred->QP, 1: gt->QG
    const float4* src = cloud ? gt : pred;
    float4* dst = cloud ? QG : QP;
    const int tid = threadIdx.x;

    __shared__ int hist[4096];
    __shared__ int part[1024];
#pragma unroll
    for (int k = 0; k < 4; ++k) hist[tid * 4 + k] = 0;
    __syncthreads();

    int keys[8];
#pragma unroll
    for (int k = 0; k < 8; ++k) {
        float4 v = src[tid * 8 + k];
        int cx = min(15, max(0, (int)floorf((v.x + 5.0f) * 1.6f)));
        int cy = min(15, max(0, (int)floorf((v.y + 5.0f) * 1.6f)));
        int cz = min(15, max(0, (int)floorf((v.z + 5.0f) * 1.6f)));
        keys[k] = (cz << 8) | (cy << 4) | cx;
        atomicAdd(&hist[keys[k]], 1);
    }
    __syncthreads();
    int h[4], s4 = 0;
#pragma unroll
    for (int k = 0; k < 4; ++k) { h[k] = hist[tid * 4 + k]; s4 += h[k]; }
    part[tid] = s4;
    __syncthreads();
    for (int off = 1; off < 1024; off <<= 1) {      // inclusive scan
        int v = (tid >= off) ? part[tid - off] : 0;
        __syncthreads();
        part[tid] += v;
        __syncthreads();
    }
    int base = part[tid] - s4;                       // exclusive
#pragma unroll
    for (int k = 0; k < 4; ++k) { hist[tid * 4 + k] = base; base += h[k]; }
    __syncthreads();
#pragma unroll
    for (int k = 0; k < 8; ++k) {
        float4 v = src[tid * 8 + k];
        int pos = atomicAdd(&hist[keys[k]], 1);
        float x = v.x * SCALE, y = v.y * SCALE, z = v.z * SCALE;
        dst[pos] = make_float4(x, y, z, fmaf(x, x, fmaf(y, y, z * z)));
    }
}

// bboxes of 32-point groups. 512 blocks: cloud = b>>8, grp = b&255.
__global__ __launch_bounds__(64) void bbox32_kernel(
    const float4* __restrict__ QP, const float4* __restrict__ QG,
    float4* __restrict__ bb32)
{
    const int b = blockIdx.x;
    const float4* q = (b >> 8) ? QG : QP;
    const int lane = threadIdx.x;
    float4 v = q[(b & 255) * 32 + (lane & 31)];
    float lx = v.x, ly = v.y, lz = v.z, hx = v.x, hy = v.y, hz = v.z;
#pragma unroll
    for (int off = 1; off <= 16; off <<= 1) {
        lx = fminf(lx, __shfl_xor(lx, off, 64));
        ly = fminf(ly, __shfl_xor(ly, off, 64));
        lz = fminf(lz, __shfl_xor(lz, off, 64));
        hx = fmaxf(hx, __shfl_xor(hx, off, 64));
        hy = fmaxf(hy, __shfl_xor(hy, off, 64));
        hz = fmaxf(hz, __shfl_xor(hz, off, 64));
    }
    if (lane == 0) {
        bb32[b * 2]     = make_float4(lx, ly, lz, 0.0f);
        bb32[b * 2 + 1] = make_float4(hx, hy, hz, 0.0f);
    }
}

// bboxes of 64-point tiles = union of two 32-groups. 1 block x 256 threads.
__global__ __launch_bounds__(256) void bbox64_kernel(
    const float4* __restrict__ bb32, float4* __restrict__ bb64)
{
    const int t = threadIdx.x;               // cloud = t>>7, tile = t&127
    const int cloud = t >> 7, tile = t & 127;
    const int s = (cloud * 256 + tile * 2) * 2;
    float4 lo0 = bb32[s], hi0 = bb32[s + 1], lo1 = bb32[s + 2], hi1 = bb32[s + 3];
    bb64[t * 2] = make_float4(fminf(lo0.x, lo1.x), fminf(lo0.y, lo1.y),
                              fminf(lo0.z, lo1.z), 0.0f);
    bb64[t * 2 + 1] = make_float4(fmaxf(hi0.x, hi1.x), fmaxf(hi0.y, hi1.y),
                                  fmaxf(hi0.z, hi1.z), 0.0f);
}

__global__ __launch_bounds__(256) void init_kernel(
    float* __restrict__ Vg, float* __restrict__ SArr, float* __restrict__ chamsum)
{
    int idx = blockIdx.x * 256 + threadIdx.x;
    if (idx < 3 * PN) Vg[idx] = 1.0f / 8192.0f;
    if (idx < 12288) SArr[idx] = -1e30f;      // keep-all until real stats exist
    if (idx == 0) *chamsum = 0.0f;
}

// One half-update for all 3 problems. Grid: 768 = 3 problems x 256 blocks.
// Block: 512 threads = 8 waves; wave w owns rowgroup (b&255) + 256*w
// (4 rows, scattered) x 64 column slots. Per-wave ballot cull of 64-col tiles.
__global__ __launch_bounds__(512) void pass_kernel(
    const float4* __restrict__ QP, const float4* __restrict__ QG,
    float* __restrict__ Vf, float* __restrict__ Vg,
    const float4* __restrict__ bb64, float* __restrict__ SArr, const int dir)
{
    const int tid = threadIdx.x;
    const int lane = tid & 63;
    const int w = __builtin_amdgcn_readfirstlane(tid >> 6);  // wave 0..7
    const int p = blockIdx.x >> 8;       // problem 0..2
    const int b = blockIdx.x & 255;

    // cloud ids: 0 = pred(QP), 1 = gt(QG)
    const int r0 = (p == 2) ? 1 : 0;     // dir0 row cloud
    const int c0 = (p == 1) ? 0 : 1;     // dir0 col cloud
    const int rowCloud = dir ? c0 : r0;
    const int colCloud = dir ? r0 : c0;
    const float4* rowQ = rowCloud ? QG : QP;
    const float4* colQ = colCloud ? QG : QP;
    float* vin  = (dir ? Vf : Vg) + p * PN;
    float* vout = (dir ? Vg : Vf) + p * PN;
    const float* SArrRow = SArr + (dir * 3 + p) * 2048;         // stale (prev iter)
    const float* SArrCol = SArr + ((dir ^ 1) * 3 + p) * 2048;   // fresh (prev pass)
    float* SArrOut = SArr + (dir * 3 + p) * 2048;

    const int rg = b + (w << 8);         // rowgroup 0..2047, scattered
    const int row0 = rg << 2;

    float r2x[4], r2y[4], r2z[4], base[4], acc[4];
    float blox = 1e30f, bloy = 1e30f, bloz = 1e30f;
    float bhix = -1e30f, bhiy = -1e30f, bhiz = -1e30f;
#pragma unroll
    for (int k = 0; k < 4; ++k) {
        float4 q = rowQ[row0 + k];
        blox = fminf(blox, q.x); bhix = fmaxf(bhix, q.x);
        bloy = fminf(bloy, q.y); bhiy = fmaxf(bhiy, q.y);
        bloz = fminf(bloz, q.z); bhiz = fmaxf(bhiz, q.z);
        r2x[k] = -2.0f * q.x; r2y[k] = -2.0f * q.y; r2z[k] = -2.0f * q.z;
        base[k] = q.w;
        acc[k] = 0.0f;
    }
    const float lsr = SArrRow[rg];       // min log2 s over these 4 rows

    __shared__ float4 sQ[TILE];
    __shared__ float  sV[TILE];
    __shared__ float  sMaxH[128];
    __shared__ float4 sBLo[128], sBHi[128];

    // prelude: per-64col-tile max log2 v and bboxes into LDS (once per block)
    if (tid < 128) {
        const float4* sa = (const float4*)SArrCol + tid * 4;   // 16 rg entries
        float4 a = sa[0], b4 = sa[1], c4 = sa[2], d4 = sa[3];
        float m = fminf(fminf(fminf(a.x, a.y), fminf(a.z, a.w)),
                  fminf(fminf(fminf(b4.x, b4.y), fminf(b4.z, b4.w)),
                  fminf(fminf(fminf(c4.x, c4.y), fminf(c4.z, c4.w)),
                        fminf(fminf(d4.x, d4.y), fminf(d4.z, d4.w)))));
        sMaxH[tid] = -13.0f - m;         // max log2 v in tile
        sBLo[tid] = bb64[(colCloud * 128 + tid) * 2];
        sBHi[tid] = bb64[(colCloud * 128 + tid) * 2 + 1];
    }

    const float4* vin4 = (const float4*)vin;
    for (int tb = 0; tb < PN; tb += TILE) {
        __syncthreads();
#pragma unroll
        for (int k = 0; k < TILE / 512; ++k) {
            int idx = tid + k * 512;
            sQ[idx] = colQ[tb + idx];     // coalesced float4
        }
        ((float4*)sV)[tid] = vin4[tb / 4 + tid];
        __syncthreads();

        // per-wave cull of this stage's 32 tiles (64 cols each)
        bool keep = false;
        if (lane < 32) {
            int t64 = (tb >> 6) + lane;
            float4 clo = sBLo[t64];
            float4 chi = sBHi[t64];
            float thr = fmaxf(sMaxH[t64] - lsr + MARGIN, 0.0f);
            float dx = fmaxf(0.0f, fmaxf(blox - chi.x, clo.x - bhix));
            float dy = fmaxf(0.0f, fmaxf(bloy - chi.y, clo.y - bhiy));
            float dz = fmaxf(0.0f, fmaxf(bloz - chi.z, clo.z - bhiz));
            float dmin2 = fmaf(dx, dx, fmaf(dy, dy, dz * dz));
            keep = dmin2 <= thr * thr;
        }
        unsigned long long mask = __ballot(keep);
        while (mask) {
            int st = __builtin_ctzll(mask);
            mask &= mask - 1;
            int col = (st << 6) + lane;
            float4 wq = sQ[col];
            float v = sV[col];
#pragma unroll
            for (int k = 0; k < 4; ++k) {
                float t = base[k] + wq.w;
                t = fmaf(r2x[k], wq.x, t);
                t = fmaf(r2y[k], wq.y, t);
                t = fmaf(r2z[k], wq.z, t);
                float d = SQRTF(fabsf(t));
                float e = EXP2F(-d);            // K_ij
                acc[k] = fmaf(e, v, acc[k]);
            }
        }
    }

    // reduce each row over the wave's 64 lanes
#pragma unroll
    for (int k = 0; k < 4; ++k) {
        float a = acc[k];
        a += __shfl_xor(a, 1, 64);  a += __shfl_xor(a, 2, 64);
        a += __shfl_xor(a, 4, 64);  a += __shfl_xor(a, 8, 64);
        a += __shfl_xor(a, 16, 64); a += __shfl_xor(a, 32, 64);
        acc[k] = a;
    }
    if (lane == 0) {
        float smin = fminf(fminf(acc[0], acc[1]), fminf(acc[2], acc[3]));
#pragma unroll
        for (int k = 0; k < 4; ++k)
            vout[row0 + k] = (1.0f / 8192.0f) / acc[k];   // u = a / (K v)
        SArrOut[rg] = LOG2F(smin);
    }
}

// chamfer = mean_i min_j ||gt_i - pred_j||^2 over scaled quads (monotone).
// 256 blocks x 512 threads: 8 row-groups (x4 rows) x 64 chunks.
__global__ __launch_bounds__(512) void chamfer_kernel(
    const float4* __restrict__ QP, const float4* __restrict__ QG,
    float* __restrict__ chamsum)
{
    const int tid = threadIdx.x;
    const int rb = blockIdx.x;
    const int r = tid & 7;
    const int c = tid >> 3;
    const int row0 = rb * 32 + r * 4;

    float r2x[4], r2y[4], r2z[4], m[4];
#pragma unroll
    for (int k = 0; k < 4; ++k) {
        float4 rq = QG[row0 + k];
        r2x[k] = -2.0f * rq.x; r2y[k] = -2.0f * rq.y; r2z[k] = -2.0f * rq.z;
        m[k] = 3.4e38f;
    }

    __shared__ float4 sQ[TILE];
    const int cbase = c * (TILE / 64);
    for (int tb = 0; tb < PN; tb += TILE) {
        __syncthreads();
#pragma unroll
        for (int k = 0; k < TILE / 512; ++k) {
            int idx = tid + k * 512;
            sQ[idx] = QP[tb + idx];
        }
        __syncthreads();
#pragma unroll 4
        for (int j = 0; j < TILE / 64; ++j) {
            int col = cbase + ((j + c) & (TILE / 64 - 1));
            float4 w = sQ[col];
#pragma unroll
            for (int k = 0; k < 4; ++k) {
                float t = fmaf(r2x[k], w.x, w.w);
                t = fmaf(r2y[k], w.y, t);
                t = fmaf(r2z[k], w.z, t);
                m[k] = fminf(m[k], t);           // min of (cc - 2 r.c)
            }
        }
    }
#pragma unroll
    for (int k = 0; k < 4; ++k) {
        m[k] = fminf(m[k], __shfl_xor(m[k], 8, 64));
        m[k] = fminf(m[k], __shfl_xor(m[k], 16, 64));
        m[k] = fminf(m[k], __shfl_xor(m[k], 32, 64));
    }
    __shared__ float red[8][33];
    const int lane = tid & 63;
    const int wave = tid >> 6;
    if (lane < 8) {
#pragma unroll
        for (int k = 0; k < 4; ++k) red[wave][lane * 4 + k] = m[k];
    }
    __syncthreads();
    if (tid < 32) {
        float mm = 3.4e38f;
#pragma unroll
        for (int w2 = 0; w2 < 8; ++w2) mm = fminf(mm, red[w2][tid]);
        float rw = QG[rb * 32 + tid].w;
        float d2 = fmaxf(mm + rw, 0.0f) * INV_S2;   // + ||r||^2, unscale
        for (int off = 16; off; off >>= 1) d2 += __shfl_xor(d2, off, 64);
        if (tid == 0) atomicAdd(chamsum, d2);
    }
}

__global__ __launch_bounds__(256) void final_kernel(
    const float* __restrict__ Vf, const float* __restrict__ Vg,
    const float* __restrict__ chamsum, float* __restrict__ out)
{
    const int tid = threadIdx.x;
    float local = 0.0f;
    for (int i = tid; i < PN; i += 256) {
        float w0 = LOG2F(Vf[i]) + LOG2F(Vg[i]);
        float w1 = LOG2F(Vf[PN + i]) + LOG2F(Vg[PN + i]);
        float w2 = LOG2F(Vf[2 * PN + i]) + LOG2F(Vg[2 * PN + i]);
        local += w0 - 0.5f * (w1 + w2);
    }
    for (int off = 32; off; off >>= 1) local += __shfl_xor(local, off, 64);
    __shared__ float red[4];
    if ((tid & 63) == 0) red[tid >> 6] = local;
    __syncthreads();
    if (tid == 0) {
        float wsum = red[0] + red[1] + red[2] + red[3];
        float emd = EPS * LN2 * wsum / 8192.0f;   // log2 -> ln; ln N terms cancel
        float cham = (*chamsum) / 8192.0f;
        out[0] = 0.2f * cham + 0.8f * emd;
    }
}

extern "C" void kernel_launch(void* const* d_in, const int* in_sizes, int n_in,
                              void* d_out, int out_size, void* d_ws, size_t ws_size,
                              hipStream_t stream)
{
    const float4* pred = (const float4*)d_in[0];   // (8192,4) f32
    const float4* gt   = (const float4*)d_in[1];
    char* ws = (char*)d_ws;
    float4* QP      = (float4*)(ws + WS_QP);
    float4* QG      = (float4*)(ws + WS_QG);
    float*  Vf      = (float*)(ws + WS_VF);
    float*  Vg      = (float*)(ws + WS_VG);
    float4* bb32    = (float4*)(ws + WS_BB32);
    float4* bb64    = (float4*)(ws + WS_BB64);
    float*  SArr    = (float*)(ws + WS_SARR);
    float*  chamsum = (float*)(ws + WS_CHAM);
    float*  out     = (float*)d_out;

    sort_kernel<<<2, 1024, 0, stream>>>(pred, gt, QP, QG);
    init_kernel<<<96, 256, 0, stream>>>(Vg, SArr, chamsum);
    bbox32_kernel<<<512, 64, 0, stream>>>(QP, QG, bb32);
    bbox64_kernel<<<1, 256, 0, stream>>>(bb32, bb64);
    chamfer_kernel<<<256, 512, 0, stream>>>(QP, QG, chamsum);
    for (int it = 0; it < 50; ++it) {
        pass_kernel<<<768, 512, 0, stream>>>(QP, QG, Vf, Vg, bb64, SArr, 0);
        pass_kernel<<<768, 512, 0, stream>>>(QP, QG, Vf, Vg, bb64, SArr, 1);
    }
    final_kernel<<<1, 256, 0, stream>>>(Vf, Vg, chamsum, out);
}

// Round 8
// 3764.931 us; speedup vs baseline: 5.0182x; 1.1094x over previous
//
#include <hip/hip_runtime.h>
#include <hip/hip_bf16.h>
#include <math.h>

// HybridLoss = 0.2 * chamfer(gt->pred) + 0.8 * sinkhorn_divergence(pred, gt)
// Sinkhorn in scaling (u-v) domain; coords pre-scaled by S = log2(e)/eps so
// K_ij = exp2(-sqrt(S^2*(d2+1e-12))): distances measured in "bits".
// R8: waves of a block own 8 CONSECUTIVE rowgroups (correlated masks ->
// near-zero barrier imbalance); block->region map is bit-reversed (+p*85)
// for cross-CU balance. Chamfer culled via home-tile seed + bbox prune.

#define PN 8192
#define EPS 0.05f
#define SCALE 28.853900817779268f        // log2(e)/eps
#define INV_S2 (1.0f / (SCALE * SCALE))
#define LN2 0.6931471805599453f
#define TILE 2048
#define MARGIN 28.0f

#define EXP2F __builtin_amdgcn_exp2f
#define SQRTF __builtin_amdgcn_sqrtf
#if defined(__has_builtin) && __has_builtin(__builtin_amdgcn_logf)
#define LOG2F __builtin_amdgcn_logf
#else
#define LOG2F log2f
#endif

__device__ __forceinline__ int bitrev8(int x) { return __brev(x) >> 24; }

// ws layout (bytes)
#define WS_QP    0          // 8192 float4 = 131072 (sorted, scaled pred)
#define WS_QG    131072     // 131072 (sorted, scaled gt)
#define WS_VF    262144     // 3*8192*4 = 98304
#define WS_VG    360448     // 98304
#define WS_BB32  458752     // 2 clouds * 256 * 2 float4 = 16384
#define WS_BB64  475136     // 2 clouds * 128 * 2 float4 = 8192
#define WS_SARR  483328     // 2 dir * 3 p * 2048 rg * 4 = 49152
#define WS_CHAM  532480     // 4

// Counting sort one cloud by 16^3 spatial cell; emits scaled quads
// (S*x, S*y, S*z, ||S*p||^2) in cell order. One block per cloud.
__global__ __launch_bounds__(1024) void sort_kernel(
    const float4* __restrict__ pred, const float4* __restrict__ gt,
    float4* __restrict__ QP, float4* __restrict__ QG)
{
    const int cloud = blockIdx.x;            // 0: pred->QP, 1: gt->QG
    const float4* src = cloud ? gt : pred;
    float4* dst = cloud ? QG : QP;
    const int tid = threadIdx.x;

    __shared__ int hist[4096];
    __shared__ int part[1024];
#pragma unroll
    for (int k = 0; k < 4; ++k) hist[tid * 4 + k] = 0;
    __syncthreads();

    int keys[8];
#pragma unroll
    for (int k = 0; k < 8; ++k) {
        float4 v = src[tid * 8 + k];
        int cx = min(15, max(0, (int)floorf((v.x + 5.0f) * 1.6f)));
        int cy = min(15, max(0, (int)floorf((v.y + 5.0f) * 1.6f)));
        int cz = min(15, max(0, (int)floorf((v.z + 5.0f) * 1.6f)));
        keys[k] = (cz << 8) | (cy << 4) | cx;
        atomicAdd(&hist[keys[k]], 1);
    }
    __syncthreads();
    int h[4], s4 = 0;
#pragma unroll
    for (int k = 0; k < 4; ++k) { h[k] = hist[tid * 4 + k]; s4 += h[k]; }
    part[tid] = s4;
    __syncthreads();
    for (int off = 1; off < 1024; off <<= 1) {      // inclusive scan
        int v = (tid >= off) ? part[tid - off] : 0;
        __syncthreads();
        part[tid] += v;
        __syncthreads();
    }
    int base = part[tid] - s4;                       // exclusive
#pragma unroll
    for (int k = 0; k < 4; ++k) { hist[tid * 4 + k] = base; base += h[k]; }
    __syncthreads();
#pragma unroll
    for (int k = 0; k < 8; ++k) {
        float4 v = src[tid * 8 + k];
        int pos = atomicAdd(&hist[keys[k]], 1);
        float x = v.x * SCALE, y = v.y * SCALE, z = v.z * SCALE;
        dst[pos] = make_float4(x, y, z, fmaf(x, x, fmaf(y, y, z * z)));
    }
}

// bboxes of 32-point groups. 512 blocks: cloud = b>>8, grp = b&255.
__global__ __launch_bounds__(64) void bbox32_kernel(
    const float4* __restrict__ QP, const float4* __restrict__ QG,
    float4* __restrict__ bb32)
{
    const int b = blockIdx.x;
    const float4* q = (b >> 8) ? QG : QP;
    const int lane = threadIdx.x;
    float4 v = q[(b & 255) * 32 + (lane & 31)];
    float lx = v.x, ly = v.y, lz = v.z, hx = v.x, hy = v.y, hz = v.z;
#pragma unroll
    for (int off = 1; off <= 16; off <<= 1) {
        lx = fminf(lx, __shfl_xor(lx, off, 64));
        ly = fminf(ly, __shfl_xor(ly, off, 64));
        lz = fminf(lz, __shfl_xor(lz, off, 64));
        hx = fmaxf(hx, __shfl_xor(hx, off, 64));
        hy = fmaxf(hy, __shfl_xor(hy, off, 64));
        hz = fmaxf(hz, __shfl_xor(hz, off, 64));
    }
    if (lane == 0) {
        bb32[b * 2]     = make_float4(lx, ly, lz, 0.0f);
        bb32[b * 2 + 1] = make_float4(hx, hy, hz, 0.0f);
    }
}

// bboxes of 64-point tiles = union of two 32-groups. 1 block x 256 threads.
__global__ __launch_bounds__(256) void bbox64_kernel(
    const float4* __restrict__ bb32, float4* __restrict__ bb64)
{
    const int t = threadIdx.x;               // cloud = t>>7, tile = t&127
    const int cloud = t >> 7, tile = t & 127;
    const int s = (cloud * 256 + tile * 2) * 2;
    float4 lo0 = bb32[s], hi0 = bb32[s + 1], lo1 = bb32[s + 2], hi1 = bb32[s + 3];
    bb64[t * 2] = make_float4(fminf(lo0.x, lo1.x), fminf(lo0.y, lo1.y),
                              fminf(lo0.z, lo1.z), 0.0f);
    bb64[t * 2 + 1] = make_float4(fmaxf(hi0.x, hi1.x), fmaxf(hi0.y, hi1.y),
                                  fmaxf(hi0.z, hi1.z), 0.0f);
}

__global__ __launch_bounds__(256) void init_kernel(
    float* __restrict__ Vg, float* __restrict__ SArr, float* __restrict__ chamsum)
{
    int idx = blockIdx.x * 256 + threadIdx.x;
    if (idx < 3 * PN) Vg[idx] = 1.0f / 8192.0f;
    if (idx < 12288) SArr[idx] = -1e30f;      // keep-all until real stats exist
    if (idx == 0) *chamsum = 0.0f;
}

// One half-update for all 3 problems. Grid: 768 = 3 problems x 256 blocks.
// Block: 512 threads = 8 waves; wave w owns rowgroup region*8+w (the block's
// 32 rows are CONSECUTIVE -> waves share masks -> no barrier imbalance).
// region = bitrev8(b) + p*85 spreads heavy regions across CUs and problems.
__global__ __launch_bounds__(512) void pass_kernel(
    const float4* __restrict__ QP, const float4* __restrict__ QG,
    float* __restrict__ Vf, float* __restrict__ Vg,
    const float4* __restrict__ bb64, float* __restrict__ SArr, const int dir)
{
    const int tid = threadIdx.x;
    const int lane = tid & 63;
    const int w = __builtin_amdgcn_readfirstlane(tid >> 6);  // wave 0..7
    const int p = blockIdx.x >> 8;       // problem 0..2
    const int b = blockIdx.x & 255;
    const int region = (bitrev8(b) + p * 85) & 255;

    // cloud ids: 0 = pred(QP), 1 = gt(QG)
    const int r0 = (p == 2) ? 1 : 0;     // dir0 row cloud
    const int c0 = (p == 1) ? 0 : 1;     // dir0 col cloud
    const int rowCloud = dir ? c0 : r0;
    const int colCloud = dir ? r0 : c0;
    const float4* rowQ = rowCloud ? QG : QP;
    const float4* colQ = colCloud ? QG : QP;
    float* vin  = (dir ? Vf : Vg) + p * PN;
    float* vout = (dir ? Vg : Vf) + p * PN;
    const float* SArrRow = SArr + (dir * 3 + p) * 2048;         // stale (prev iter)
    const float* SArrCol = SArr + ((dir ^ 1) * 3 + p) * 2048;   // fresh (prev pass)
    float* SArrOut = SArr + (dir * 3 + p) * 2048;

    const int rg = region * 8 + w;       // rowgroup 0..2047 (block-consecutive)
    const int row0 = rg << 2;

    float r2x[4], r2y[4], r2z[4], base[4], acc[4];
    float blox = 1e30f, bloy = 1e30f, bloz = 1e30f;
    float bhix = -1e30f, bhiy = -1e30f, bhiz = -1e30f;
#pragma unroll
    for (int k = 0; k < 4; ++k) {
        float4 q = rowQ[row0 + k];
        blox = fminf(blox, q.x); bhix = fmaxf(bhix, q.x);
        bloy = fminf(bloy, q.y); bhiy = fmaxf(bhiy, q.y);
        bloz = fminf(bloz, q.z); bhiz = fmaxf(bhiz, q.z);
        r2x[k] = -2.0f * q.x; r2y[k] = -2.0f * q.y; r2z[k] = -2.0f * q.z;
        base[k] = q.w;
        acc[k] = 0.0f;
    }
    const float lsr = SArrRow[rg];       // min log2 s over these 4 rows

    __shared__ float4 sQ[TILE];
    __shared__ float  sV[TILE];
    __shared__ float  sMaxH[128];
    __shared__ float4 sBLo[128], sBHi[128];

    // prelude: per-64col-tile max log2 v and bboxes into LDS (once per block)
    if (tid < 128) {
        const float4* sa = (const float4*)SArrCol + tid * 4;   // 16 rg entries
        float4 a = sa[0], b4 = sa[1], c4 = sa[2], d4 = sa[3];
        float m = fminf(fminf(fminf(a.x, a.y), fminf(a.z, a.w)),
                  fminf(fminf(fminf(b4.x, b4.y), fminf(b4.z, b4.w)),
                  fminf(fminf(fminf(c4.x, c4.y), fminf(c4.z, c4.w)),
                        fminf(fminf(d4.x, d4.y), fminf(d4.z, d4.w)))));
        sMaxH[tid] = -13.0f - m;         // max log2 v in tile
        sBLo[tid] = bb64[(colCloud * 128 + tid) * 2];
        sBHi[tid] = bb64[(colCloud * 128 + tid) * 2 + 1];
    }

    const float4* vin4 = (const float4*)vin;
    for (int tb = 0; tb < PN; tb += TILE) {
        __syncthreads();
#pragma unroll
        for (int k = 0; k < TILE / 512; ++k) {
            int idx = tid + k * 512;
            sQ[idx] = colQ[tb + idx];     // coalesced float4
        }
        ((float4*)sV)[tid] = vin4[tb / 4 + tid];
        __syncthreads();

        // per-wave cull of this stage's 32 tiles (64 cols each)
        bool keep = false;
        if (lane < 32) {
            int t64 = (tb >> 6) + lane;
            float4 clo = sBLo[t64];
            float4 chi = sBHi[t64];
            float thr = fmaxf(sMaxH[t64] - lsr + MARGIN, 0.0f);
            float dx = fmaxf(0.0f, fmaxf(blox - chi.x, clo.x - bhix));
            float dy = fmaxf(0.0f, fmaxf(bloy - chi.y, clo.y - bhiy));
            float dz = fmaxf(0.0f, fmaxf(bloz - chi.z, clo.z - bhiz));
            float dmin2 = fmaf(dx, dx, fmaf(dy, dy, dz * dz));
            keep = dmin2 <= thr * thr;
        }
        unsigned long long mask = __ballot(keep);
        while (mask) {
            int st = __builtin_ctzll(mask);
            mask &= mask - 1;
            int col = (st << 6) + lane;
            float4 wq = sQ[col];
            float v = sV[col];
#pragma unroll
            for (int k = 0; k < 4; ++k) {
                float t = base[k] + wq.w;
                t = fmaf(r2x[k], wq.x, t);
                t = fmaf(r2y[k], wq.y, t);
                t = fmaf(r2z[k], wq.z, t);
                float d = SQRTF(fabsf(t));
                float e = EXP2F(-d);            // K_ij
                acc[k] = fmaf(e, v, acc[k]);
            }
        }
    }

    // reduce each row over the wave's 64 lanes
#pragma unroll
    for (int k = 0; k < 4; ++k) {
        float a = acc[k];
        a += __shfl_xor(a, 1, 64);  a += __shfl_xor(a, 2, 64);
        a += __shfl_xor(a, 4, 64);  a += __shfl_xor(a, 8, 64);
        a += __shfl_xor(a, 16, 64); a += __shfl_xor(a, 32, 64);
        acc[k] = a;
    }
    if (lane == 0) {
        float smin = fminf(fminf(acc[0], acc[1]), fminf(acc[2], acc[3]));
#pragma unroll
        for (int k = 0; k < 4; ++k)
            vout[row0 + k] = (1.0f / 8192.0f) / acc[k];   // u = a / (K v)
        SArrOut[rg] = LOG2F(smin);
    }
}

// chamfer = mean_i min_j ||gt_i - pred_j||^2, culled: seed each 4-row wave
// from its bbox-nearest "home" tile, then visit only tiles whose bbox dist
// beats the current bound (lossless: the true NN's tile always passes).
// 256 blocks x 512 threads; wave w owns rowgroup bitrev8(b)*8+w.
__global__ __launch_bounds__(512) void chamfer_kernel(
    const float4* __restrict__ QP, const float4* __restrict__ QG,
    const float4* __restrict__ bb64, float* __restrict__ chamsum)
{
    const int tid = threadIdx.x;
    const int lane = tid & 63;
    const int w = __builtin_amdgcn_readfirstlane(tid >> 6);
    const int rg = bitrev8(blockIdx.x) * 8 + w;   // 0..2047
    const int row0 = rg << 2;

    float r2x[4], r2y[4], r2z[4], base[4], m[4];
    float blox = 1e30f, bloy = 1e30f, bloz = 1e30f;
    float bhix = -1e30f, bhiy = -1e30f, bhiz = -1e30f;
#pragma unroll
    for (int k = 0; k < 4; ++k) {
        float4 q = QG[row0 + k];
        blox = fminf(blox, q.x); bhix = fmaxf(bhix, q.x);
        bloy = fminf(bloy, q.y); bhiy = fmaxf(bhiy, q.y);
        bloz = fminf(bloz, q.z); bhiz = fmaxf(bhiz, q.z);
        r2x[k] = -2.0f * q.x; r2y[k] = -2.0f * q.y; r2z[k] = -2.0f * q.z;
        base[k] = q.w;
        m[k] = 3.4e38f;
    }
    const float bcx = (blox + bhix) * 0.5f;
    const float bcy = (bloy + bhiy) * 0.5f;
    const float bcz = (bloz + bhiz) * 0.5f;

    // home tile: nearest bbox center (pred tiles = cloud 0)
    float bd = 1e30f; int bi = 0;
#pragma unroll
    for (int h = 0; h < 2; ++h) {
        int t = lane + h * 64;
        float4 lo = bb64[t * 2], hi = bb64[t * 2 + 1];
        float cx = (lo.x + hi.x) * 0.5f - bcx;
        float cy = (lo.y + hi.y) * 0.5f - bcy;
        float cz = (lo.z + hi.z) * 0.5f - bcz;
        float d = fmaf(cx, cx, fmaf(cy, cy, cz * cz));
        if (d < bd) { bd = d; bi = t; }
    }
#pragma unroll
    for (int off = 1; off <= 32; off <<= 1) {
        float od = __shfl_xor(bd, off, 64);
        int oi = __shfl_xor(bi, off, 64);
        if (od < bd) { bd = od; bi = oi; }
    }
    const int home = __builtin_amdgcn_readfirstlane(bi);

    // seed from home tile
    {
        float4 wq = QP[home * 64 + lane];
#pragma unroll
        for (int k = 0; k < 4; ++k) {
            float t = fmaf(r2x[k], wq.x, wq.w);
            t = fmaf(r2y[k], wq.y, t);
            t = fmaf(r2z[k], wq.z, t);
            m[k] = fminf(m[k], t);
        }
    }
    float Bmax = -3.4e38f;
#pragma unroll
    for (int k = 0; k < 4; ++k) {
        float mr = m[k];
#pragma unroll
        for (int off = 1; off <= 32; off <<= 1)
            mr = fminf(mr, __shfl_xor(mr, off, 64));
        m[k] = mr;
        Bmax = fmaxf(Bmax, mr + base[k]);   // true scaled d2 bound
    }

    // cull + walk survivors
#pragma unroll
    for (int h = 0; h < 2; ++h) {
        int t = lane + h * 64;
        float4 lo = bb64[t * 2], hi = bb64[t * 2 + 1];
        float dx = fmaxf(0.0f, fmaxf(blox - hi.x, lo.x - bhix));
        float dy = fmaxf(0.0f, fmaxf(bloy - hi.y, lo.y - bhiy));
        float dz = fmaxf(0.0f, fmaxf(bloz - hi.z, lo.z - bhiz));
        float dmin2 = fmaf(dx, dx, fmaf(dy, dy, dz * dz));
        bool keep = (dmin2 < Bmax) && (t != home);
        unsigned long long mask = __ballot(keep);
        while (mask) {
            int st = __builtin_ctzll(mask);
            mask &= mask - 1;
            float4 wq = QP[((h << 6) + st) * 64 + lane];
#pragma unroll
            for (int k = 0; k < 4; ++k) {
                float tt = fmaf(r2x[k], wq.x, wq.w);
                tt = fmaf(r2y[k], wq.y, tt);
                tt = fmaf(r2z[k], wq.z, tt);
                m[k] = fminf(m[k], tt);
            }
        }
    }
    float ch = 0.0f;
#pragma unroll
    for (int k = 0; k < 4; ++k) {
        float mr = m[k];
#pragma unroll
        for (int off = 1; off <= 32; off <<= 1)
            mr = fminf(mr, __shfl_xor(mr, off, 64));
        ch += fmaxf(mr + base[k], 0.0f) * INV_S2;
    }
    __shared__ float red[8];
    if (lane == 0) red[w] = ch;
    __syncthreads();
    if (tid == 0) {
        float s = 0.0f;
#pragma unroll
        for (int k = 0; k < 8; ++k) s += red[k];
        atomicAdd(chamsum, s);
    }
}

__global__ __launch_bounds__(256) void final_kernel(
    const float* __restrict__ Vf, const float* __restrict__ Vg,
    const float* __restrict__ chamsum, float* __restrict__ out)
{
    const int tid = threadIdx.x;
    float local = 0.0f;
    for (int i = tid; i < PN; i += 256) {
        float w0 = LOG2F(Vf[i]) + LOG2F(Vg[i]);
        float w1 = LOG2F(Vf[PN + i]) + LOG2F(Vg[PN + i]);
        float w2 = LOG2F(Vf[2 * PN + i]) + LOG2F(Vg[2 * PN + i]);
        local += w0 - 0.5f * (w1 + w2);
    }
    for (int off = 32; off; off >>= 1) local += __shfl_xor(local, off, 64);
    __shared__ float red[4];
    if ((tid & 63) == 0) red[tid >> 6] = local;
    __syncthreads();
    if (tid == 0) {
        float wsum = red[0] + red[1] + red[2] + red[3];
        float emd = EPS * LN2 * wsum / 8192.0f;   // log2 -> ln; ln N terms cancel
        float cham = (*chamsum) / 8192.0f;
        out[0] = 0.2f * cham + 0.8f * emd;
    }
}

extern "C" void kernel_launch(void* const* d_in, const int* in_sizes, int n_in,
                              void* d_out, int out_size, void* d_ws, size_t ws_size,
                              hipStream_t stream)
{
    const float4* pred = (const float4*)d_in[0];   // (8192,4) f32
    const float4* gt   = (const float4*)d_in[1];
    char* ws = (char*)d_ws;
    float4* QP      = (float4*)(ws + WS_QP);
    float4* QG      = (float4*)(ws + WS_QG);
    float*  Vf      = (float*)(ws + WS_VF);
    float*  Vg      = (float*)(ws + WS_VG);
    float4* bb32    = (float4*)(ws + WS_BB32);
    float4* bb64    = (float4*)(ws + WS_BB64);
    float*  SArr    = (float*)(ws + WS_SARR);
    float*  chamsum = (float*)(ws + WS_CHAM);
    float*  out     = (float*)d_out;

    sort_kernel<<<2, 1024, 0, stream>>>(pred, gt, QP, QG);
    init_kernel<<<96, 256, 0, stream>>>(Vg, SArr, chamsum);
    bbox32_kernel<<<512, 64, 0, stream>>>(QP, QG, bb32);
    bbox64_kernel<<<1, 256, 0, stream>>>(bb32, bb64);
    chamfer_kernel<<<256, 512, 0, stream>>>(QP, QG, bb64, chamsum);
    for (int it = 0; it < 50; ++it) {
        pass_kernel<<<768, 512, 0, stream>>>(QP, QG, Vf, Vg, bb64, SArr, 0);
        pass_kernel<<<768, 512, 0, stream>>>(QP, QG, Vf, Vg, bb64, SArr, 1);
    }
    final_kernel<<<1, 256, 0, stream>>>(Vf, Vg, chamsum, out);
}

// Round 9
// 3742.633 us; speedup vs baseline: 5.0481x; 1.0060x over previous
//
#include <hip/hip_runtime.h>
#include <hip/hip_bf16.h>
#include <math.h>

// HybridLoss = 0.2 * chamfer(gt->pred) + 0.8 * sinkhorn_divergence(pred, gt)
// Sinkhorn in scaling (u-v) domain; coords pre-scaled by S = log2(e)/eps so
// K_ij = exp2(-sqrt(S^2*(d2+1e-12))): distances measured in "bits".
// R9: 32-col subtile culling (bb32 boxes + per-subtile max log2 v at
// 8-rowgroup granularity), MARGIN 25. Wave processes two kept subtiles per
// iteration (half-wave each), popped pairwise from the ballot mask.

#define PN 8192
#define EPS 0.05f
#define SCALE 28.853900817779268f        // log2(e)/eps
#define INV_S2 (1.0f / (SCALE * SCALE))
#define LN2 0.6931471805599453f
#define TILE 2048
#define MARGIN 25.0f

#define EXP2F __builtin_amdgcn_exp2f
#define SQRTF __builtin_amdgcn_sqrtf
#if defined(__has_builtin) && __has_builtin(__builtin_amdgcn_logf)
#define LOG2F __builtin_amdgcn_logf
#else
#define LOG2F log2f
#endif

__device__ __forceinline__ int bitrev8(int x) { return __brev(x) >> 24; }

// ws layout (bytes)
#define WS_QP    0          // 8192 float4 = 131072 (sorted, scaled pred)
#define WS_QG    131072     // 131072 (sorted, scaled gt)
#define WS_VF    262144     // 3*8192*4 = 98304
#define WS_VG    360448     // 98304
#define WS_BB32  458752     // 2 clouds * 256 * 2 float4 = 16384
#define WS_BB64  475136     // 2 clouds * 128 * 2 float4 = 8192
#define WS_SARR  483328     // 2 dir * 3 p * 2048 rg * 4 = 49152
#define WS_CHAM  532480     // 4

// Counting sort one cloud by 16^3 spatial cell; emits scaled quads
// (S*x, S*y, S*z, ||S*p||^2) in cell order. One block per cloud.
__global__ __launch_bounds__(1024) void sort_kernel(
    const float4* __restrict__ pred, const float4* __restrict__ gt,
    float4* __restrict__ QP, float4* __restrict__ QG)
{
    const int cloud = blockIdx.x;            // 0: pred->QP, 1: gt->QG
    const float4* src = cloud ? gt : pred;
    float4* dst = cloud ? QG : QP;
    const int tid = threadIdx.x;

    __shared__ int hist[4096];
    __shared__ int part[1024];
#pragma unroll
    for (int k = 0; k < 4; ++k) hist[tid * 4 + k] = 0;
    __syncthreads();

    int keys[8];
#pragma unroll
    for (int k = 0; k < 8; ++k) {
        float4 v = src[tid * 8 + k];
        int cx = min(15, max(0, (int)floorf((v.x + 5.0f) * 1.6f)));
        int cy = min(15, max(0, (int)floorf((v.y + 5.0f) * 1.6f)));
        int cz = min(15, max(0, (int)floorf((v.z + 5.0f) * 1.6f)));
        keys[k] = (cz << 8) | (cy << 4) | cx;
        atomicAdd(&hist[keys[k]], 1);
    }
    __syncthreads();
    int h[4], s4 = 0;
#pragma unroll
    for (int k = 0; k < 4; ++k) { h[k] = hist[tid * 4 + k]; s4 += h[k]; }
    part[tid] = s4;
    __syncthreads();
    for (int off = 1; off < 1024; off <<= 1) {      // inclusive scan
        int v = (tid >= off) ? part[tid - off] : 0;
        __syncthreads();
        part[tid] += v;
        __syncthreads();
    }
    int base = part[tid] - s4;                       // exclusive
#pragma unroll
    for (int k = 0; k < 4; ++k) { hist[tid * 4 + k] = base; base += h[k]; }
    __syncthreads();
#pragma unroll
    for (int k = 0; k < 8; ++k) {
        float4 v = src[tid * 8 + k];
        int pos = atomicAdd(&hist[keys[k]], 1);
        float x = v.x * SCALE, y = v.y * SCALE, z = v.z * SCALE;
        dst[pos] = make_float4(x, y, z, fmaf(x, x, fmaf(y, y, z * z)));
    }
}

// bboxes of 32-point groups. 512 blocks: cloud = b>>8, grp = b&255.
__global__ __launch_bounds__(64) void bbox32_kernel(
    const float4* __restrict__ QP, const float4* __restrict__ QG,
    float4* __restrict__ bb32)
{
    const int b = blockIdx.x;
    const float4* q = (b >> 8) ? QG : QP;
    const int lane = threadIdx.x;
    float4 v = q[(b & 255) * 32 + (lane & 31)];
    float lx = v.x, ly = v.y, lz = v.z, hx = v.x, hy = v.y, hz = v.z;
#pragma unroll
    for (int off = 1; off <= 16; off <<= 1) {
        lx = fminf(lx, __shfl_xor(lx, off, 64));
        ly = fminf(ly, __shfl_xor(ly, off, 64));
        lz = fminf(lz, __shfl_xor(lz, off, 64));
        hx = fmaxf(hx, __shfl_xor(hx, off, 64));
        hy = fmaxf(hy, __shfl_xor(hy, off, 64));
        hz = fmaxf(hz, __shfl_xor(hz, off, 64));
    }
    if (lane == 0) {
        bb32[b * 2]     = make_float4(lx, ly, lz, 0.0f);
        bb32[b * 2 + 1] = make_float4(hx, hy, hz, 0.0f);
    }
}

// bboxes of 64-point tiles = union of two 32-groups. 1 block x 256 threads.
__global__ __launch_bounds__(256) void bbox64_kernel(
    const float4* __restrict__ bb32, float4* __restrict__ bb64)
{
    const int t = threadIdx.x;               // cloud = t>>7, tile = t&127
    const int cloud = t >> 7, tile = t & 127;
    const int s = (cloud * 256 + tile * 2) * 2;
    float4 lo0 = bb32[s], hi0 = bb32[s + 1], lo1 = bb32[s + 2], hi1 = bb32[s + 3];
    bb64[t * 2] = make_float4(fminf(lo0.x, lo1.x), fminf(lo0.y, lo1.y),
                              fminf(lo0.z, lo1.z), 0.0f);
    bb64[t * 2 + 1] = make_float4(fmaxf(hi0.x, hi1.x), fmaxf(hi0.y, hi1.y),
                                  fmaxf(hi0.z, hi1.z), 0.0f);
}

__global__ __launch_bounds__(256) void init_kernel(
    float* __restrict__ Vg, float* __restrict__ SArr, float* __restrict__ chamsum)
{
    int idx = blockIdx.x * 256 + threadIdx.x;
    if (idx < 3 * PN) Vg[idx] = 1.0f / 8192.0f;
    if (idx < 12288) SArr[idx] = -1e30f;      // keep-all until real stats exist
    if (idx == 0) *chamsum = 0.0f;
}

// One half-update for all 3 problems. Grid: 768 = 3 problems x 256 blocks.
// Block: 512 threads = 8 waves; wave w owns rowgroup region*8+w (block rows
// consecutive -> correlated masks -> low barrier imbalance).
// Per stage: ballot over 64 32-col subtiles; pop TWO kept subtiles per
// inner iteration (lanes 0-31 / 32-63); odd tail zeroes v on upper half.
__global__ __launch_bounds__(512) void pass_kernel(
    const float4* __restrict__ QP, const float4* __restrict__ QG,
    float* __restrict__ Vf, float* __restrict__ Vg,
    const float4* __restrict__ bb32, float* __restrict__ SArr, const int dir)
{
    const int tid = threadIdx.x;
    const int lane = tid & 63;
    const bool upper = lane >= 32;
    const int w = __builtin_amdgcn_readfirstlane(tid >> 6);  // wave 0..7
    const int p = blockIdx.x >> 8;       // problem 0..2
    const int b = blockIdx.x & 255;
    const int region = (bitrev8(b) + p * 85) & 255;

    // cloud ids: 0 = pred(QP), 1 = gt(QG)
    const int r0 = (p == 2) ? 1 : 0;     // dir0 row cloud
    const int c0 = (p == 1) ? 0 : 1;     // dir0 col cloud
    const int rowCloud = dir ? c0 : r0;
    const int colCloud = dir ? r0 : c0;
    const float4* rowQ = rowCloud ? QG : QP;
    const float4* colQ = colCloud ? QG : QP;
    float* vin  = (dir ? Vf : Vg) + p * PN;
    float* vout = (dir ? Vg : Vf) + p * PN;
    const float* SArrRow = SArr + (dir * 3 + p) * 2048;         // stale (prev iter)
    const float* SArrCol = SArr + ((dir ^ 1) * 3 + p) * 2048;   // fresh (prev pass)
    float* SArrOut = SArr + (dir * 3 + p) * 2048;

    const int rg = region * 8 + w;       // rowgroup 0..2047 (block-consecutive)
    const int row0 = rg << 2;

    float r2x[4], r2y[4], r2z[4], base[4], acc[4];
    float blox = 1e30f, bloy = 1e30f, bloz = 1e30f;
    float bhix = -1e30f, bhiy = -1e30f, bhiz = -1e30f;
#pragma unroll
    for (int k = 0; k < 4; ++k) {
        float4 q = rowQ[row0 + k];
        blox = fminf(blox, q.x); bhix = fmaxf(bhix, q.x);
        bloy = fminf(bloy, q.y); bhiy = fmaxf(bhiy, q.y);
        bloz = fminf(bloz, q.z); bhiz = fmaxf(bhiz, q.z);
        r2x[k] = -2.0f * q.x; r2y[k] = -2.0f * q.y; r2z[k] = -2.0f * q.z;
        base[k] = q.w;
        acc[k] = 0.0f;
    }
    const float lsr = SArrRow[rg];       // min log2 s over these 4 rows

    __shared__ float4 sQ[TILE];
    __shared__ float  sV[TILE];
    __shared__ float  sMaxH[256];
    __shared__ float4 sBLo[256], sBHi[256];

    // prelude: per-32col-subtile max log2 v + bboxes into LDS (once/block)
    if (tid < 256) {
        const float4* sa4 = (const float4*)SArrCol;
        float4 a = sa4[tid * 2], b4 = sa4[tid * 2 + 1];   // 8 rowgroup mins
        float m = fminf(fminf(fminf(a.x, a.y), fminf(a.z, a.w)),
                        fminf(fminf(b4.x, b4.y), fminf(b4.z, b4.w)));
        sMaxH[tid] = -13.0f - m;         // max log2 v in subtile
        sBLo[tid] = bb32[(colCloud * 256 + tid) * 2];
        sBHi[tid] = bb32[(colCloud * 256 + tid) * 2 + 1];
    }

    const float4* vin4 = (const float4*)vin;
    for (int tb = 0; tb < PN; tb += TILE) {
        __syncthreads();
#pragma unroll
        for (int k = 0; k < TILE / 512; ++k) {
            int idx = tid + k * 512;
            sQ[idx] = colQ[tb + idx];     // coalesced float4
        }
        ((float4*)sV)[tid] = vin4[tb / 4 + tid];
        __syncthreads();

        // per-wave cull of this stage's 64 subtiles (32 cols each)
        bool keep;
        {
            int t32 = (tb >> 5) + lane;   // global subtile id
            float4 clo = sBLo[t32];
            float4 chi = sBHi[t32];
            float thr = fmaxf(sMaxH[t32] - lsr + MARGIN, 0.0f);
            float dx = fmaxf(0.0f, fmaxf(blox - chi.x, clo.x - bhix));
            float dy = fmaxf(0.0f, fmaxf(bloy - chi.y, clo.y - bhiy));
            float dz = fmaxf(0.0f, fmaxf(bloz - chi.z, clo.z - bhiz));
            float dmin2 = fmaf(dx, dx, fmaf(dy, dy, dz * dz));
            keep = dmin2 <= thr * thr;
        }
        unsigned long long mask = __ballot(keep);
        while (mask) {
            int stA = __builtin_ctzll(mask);
            mask &= mask - 1;
            int stB = stA;
            bool hasB = (mask != 0);
            if (hasB) { stB = __builtin_ctzll(mask); mask &= mask - 1; }
            int st = upper ? stB : stA;           // local subtile 0..63
            int col = (st << 5) + (lane & 31);
            float4 wq = sQ[col];
            float v = sV[col];
            if (upper && !hasB) v = 0.0f;         // odd tail: no double count
#pragma unroll
            for (int k = 0; k < 4; ++k) {
                float t = base[k] + wq.w;
                t = fmaf(r2x[k], wq.x, t);
                t = fmaf(r2y[k], wq.y, t);
                t = fmaf(r2z[k], wq.z, t);
                float d = SQRTF(fabsf(t));
                float e = EXP2F(-d);              // K_ij
                acc[k] = fmaf(e, v, acc[k]);
            }
        }
    }

    // reduce each row over the wave's 64 lanes
#pragma unroll
    for (int k = 0; k < 4; ++k) {
        float a = acc[k];
        a += __shfl_xor(a, 1, 64);  a += __shfl_xor(a, 2, 64);
        a += __shfl_xor(a, 4, 64);  a += __shfl_xor(a, 8, 64);
        a += __shfl_xor(a, 16, 64); a += __shfl_xor(a, 32, 64);
        acc[k] = a;
    }
    if (lane == 0) {
        float smin = fminf(fminf(acc[0], acc[1]), fminf(acc[2], acc[3]));
#pragma unroll
        for (int k = 0; k < 4; ++k)
            vout[row0 + k] = (1.0f / 8192.0f) / acc[k];   // u = a / (K v)
        SArrOut[rg] = LOG2F(smin);
    }
}

// chamfer = mean_i min_j ||gt_i - pred_j||^2, culled: seed each 4-row wave
// from its bbox-nearest "home" tile, then visit only tiles whose bbox dist
// beats the current bound (lossless: the true NN's tile always passes).
__global__ __launch_bounds__(512) void chamfer_kernel(
    const float4* __restrict__ QP, const float4* __restrict__ QG,
    const float4* __restrict__ bb64, float* __restrict__ chamsum)
{
    const int tid = threadIdx.x;
    const int lane = tid & 63;
    const int w = __builtin_amdgcn_readfirstlane(tid >> 6);
    const int rg = bitrev8(blockIdx.x) * 8 + w;   // 0..2047
    const int row0 = rg << 2;

    float r2x[4], r2y[4], r2z[4], base[4], m[4];
    float blox = 1e30f, bloy = 1e30f, bloz = 1e30f;
    float bhix = -1e30f, bhiy = -1e30f, bhiz = -1e30f;
#pragma unroll
    for (int k = 0; k < 4; ++k) {
        float4 q = QG[row0 + k];
        blox = fminf(blox, q.x); bhix = fmaxf(bhix, q.x);
        bloy = fminf(bloy, q.y); bhiy = fmaxf(bhiy, q.y);
        bloz = fminf(bloz, q.z); bhiz = fmaxf(bhiz, q.z);
        r2x[k] = -2.0f * q.x; r2y[k] = -2.0f * q.y; r2z[k] = -2.0f * q.z;
        base[k] = q.w;
        m[k] = 3.4e38f;
    }
    const float bcx = (blox + bhix) * 0.5f;
    const float bcy = (bloy + bhiy) * 0.5f;
    const float bcz = (bloz + bhiz) * 0.5f;

    // home tile: nearest bbox center (pred tiles = cloud 0)
    float bd = 1e30f; int bi = 0;
#pragma unroll
    for (int h = 0; h < 2; ++h) {
        int t = lane + h * 64;
        float4 lo = bb64[t * 2], hi = bb64[t * 2 + 1];
        float cx = (lo.x + hi.x) * 0.5f - bcx;
        float cy = (lo.y + hi.y) * 0.5f - bcy;
        float cz = (lo.z + hi.z) * 0.5f - bcz;
        float d = fmaf(cx, cx, fmaf(cy, cy, cz * cz));
        if (d < bd) { bd = d; bi = t; }
    }
#pragma unroll
    for (int off = 1; off <= 32; off <<= 1) {
        float od = __shfl_xor(bd, off, 64);
        int oi = __shfl_xor(bi, off, 64);
        if (od < bd) { bd = od; bi = oi; }
    }
    const int home = __builtin_amdgcn_readfirstlane(bi);

    // seed from home tile
    {
        float4 wq = QP[home * 64 + lane];
#pragma unroll
        for (int k = 0; k < 4; ++k) {
            float t = fmaf(r2x[k], wq.x, wq.w);
            t = fmaf(r2y[k], wq.y, t);
            t = fmaf(r2z[k], wq.z, t);
            m[k] = fminf(m[k], t);
        }
    }
    float Bmax = -3.4e38f;
#pragma unroll
    for (int k = 0; k < 4; ++k) {
        float mr = m[k];
#pragma unroll
        for (int off = 1; off <= 32; off <<= 1)
            mr = fminf(mr, __shfl_xor(mr, off, 64));
        m[k] = mr;
        Bmax = fmaxf(Bmax, mr + base[k]);   // true scaled d2 bound
    }

    // cull + walk survivors
#pragma unroll
    for (int h = 0; h < 2; ++h) {
        int t = lane + h * 64;
        float4 lo = bb64[t * 2], hi = bb64[t * 2 + 1];
        float dx = fmaxf(0.0f, fmaxf(blox - hi.x, lo.x - bhix));
        float dy = fmaxf(0.0f, fmaxf(bloy - hi.y, lo.y - bhiy));
        float dz = fmaxf(0.0f, fmaxf(bloz - hi.z, lo.z - bhiz));
        float dmin2 = fmaf(dx, dx, fmaf(dy, dy, dz * dz));
        bool keep = (dmin2 < Bmax) && (t != home);
        unsigned long long mask = __ballot(keep);
        while (mask) {
            int st = __builtin_ctzll(mask);
            mask &= mask - 1;
            float4 wq = QP[((h << 6) + st) * 64 + lane];
#pragma unroll
            for (int k = 0; k < 4; ++k) {
                float tt = fmaf(r2x[k], wq.x, wq.w);
                tt = fmaf(r2y[k], wq.y, tt);
                tt = fmaf(r2z[k], wq.z, tt);
                m[k] = fminf(m[k], tt);
            }
        }
    }
    float ch = 0.0f;
#pragma unroll
    for (int k = 0; k < 4; ++k) {
        float mr = m[k];
#pragma unroll
        for (int off = 1; off <= 32; off <<= 1)
            mr = fminf(mr, __shfl_xor(mr, off, 64));
        ch += fmaxf(mr + base[k], 0.0f) * INV_S2;
    }
    __shared__ float red[8];
    if (lane == 0) red[w] = ch;
    __syncthreads();
    if (tid == 0) {
        float s = 0.0f;
#pragma unroll
        for (int k = 0; k < 8; ++k) s += red[k];
        atomicAdd(chamsum, s);
    }
}

__global__ __launch_bounds__(256) void final_kernel(
    const float* __restrict__ Vf, const float* __restrict__ Vg,
    const float* __restrict__ chamsum, float* __restrict__ out)
{
    const int tid = threadIdx.x;
    float local = 0.0f;
    for (int i = tid; i < PN; i += 256) {
        float w0 = LOG2F(Vf[i]) + LOG2F(Vg[i]);
        float w1 = LOG2F(Vf[PN + i]) + LOG2F(Vg[PN + i]);
        float w2 = LOG2F(Vf[2 * PN + i]) + LOG2F(Vg[2 * PN + i]);
        local += w0 - 0.5f * (w1 + w2);
    }
    for (int off = 32; off; off >>= 1) local += __shfl_xor(local, off, 64);
    __shared__ float red[4];
    if ((tid & 63) == 0) red[tid >> 6] = local;
    __syncthreads();
    if (tid == 0) {
        float wsum = red[0] + red[1] + red[2] + red[3];
        float emd = EPS * LN2 * wsum / 8192.0f;   // log2 -> ln; ln N terms cancel
        float cham = (*chamsum) / 8192.0f;
        out[0] = 0.2f * cham + 0.8f * emd;
    }
}

extern "C" void kernel_launch(void* const* d_in, const int* in_sizes, int n_in,
                              void* d_out, int out_size, void* d_ws, size_t ws_size,
                              hipStream_t stream)
{
    const float4* pred = (const float4*)d_in[0];   // (8192,4) f32
    const float4* gt   = (const float4*)d_in[1];
    char* ws = (char*)d_ws;
    float4* QP      = (float4*)(ws + WS_QP);
    float4* QG      = (float4*)(ws + WS_QG);
    float*  Vf      = (float*)(ws + WS_VF);
    float*  Vg      = (float*)(ws + WS_VG);
    float4* bb32    = (float4*)(ws + WS_BB32);
    float4* bb64    = (float4*)(ws + WS_BB64);
    float*  SArr    = (float*)(ws + WS_SARR);
    float*  chamsum = (float*)(ws + WS_CHAM);
    float*  out     = (float*)d_out;

    sort_kernel<<<2, 1024, 0, stream>>>(pred, gt, QP, QG);
    init_kernel<<<96, 256, 0, stream>>>(Vg, SArr, chamsum);
    bbox32_kernel<<<512, 64, 0, stream>>>(QP, QG, bb32);
    bbox64_kernel<<<1, 256, 0, stream>>>(bb32, bb64);
    chamfer_kernel<<<256, 512, 0, stream>>>(QP, QG, bb64, chamsum);
    for (int it = 0; it < 50; ++it) {
        pass_kernel<<<768, 512, 0, stream>>>(QP, QG, Vf, Vg, bb32, SArr, 0);
        pass_kernel<<<768, 512, 0, stream>>>(QP, QG, Vf, Vg, bb32, SArr, 1);
    }
    final_kernel<<<1, 256, 0, stream>>>(Vf, Vg, chamsum, out);
}